// Round 6
// baseline (1014.115 us; speedup 1.0000x reference)
//
#include <hip/hip_runtime.h>

#define SENT32 0x7FFFFFFF
#define IDMASK 0x1FFFF
#define RSHIFT 17
#define NLEVELS 16

__device__ __forceinline__ unsigned fkey(float f) {
    unsigned u = __float_as_uint(f);
    return (u & 0x80000000u) ? ~u : (u | 0x80000000u);
}
__device__ __forceinline__ float funkey(unsigned k) {
    unsigned u = (k & 0x80000000u) ? (k & 0x7FFFFFFFu) : ~k;
    return __uint_as_float(u);
}

// ---- 1. elevation: elev = x @ W + b, f64 accumulation, wave-per-row ----
__global__ __launch_bounds__(256) void k_matvec(const float* __restrict__ x,
                                                const float* __restrict__ W,
                                                const float* __restrict__ b,
                                                double* __restrict__ elev64,
                                                float* __restrict__ elev32,
                                                int N, int C) {
    int lane = threadIdx.x & 63;
    int wib  = threadIdx.x >> 6;
    int row  = blockIdx.x * (blockDim.x >> 6) + wib;
    if (row >= N) return;
    const float* xr = x + (size_t)row * C;
    double s = 0.0;
    for (int c = lane; c < C; c += 64) s += (double)xr[c] * (double)W[c];
#pragma unroll
    for (int off = 32; off > 0; off >>= 1) s += __shfl_down(s, off, 64);
    if (lane == 0) {
        double v = s + (double)b[0];
        elev64[row] = v;
        elev32[row] = (float)v;
    }
}

// ---- 2. edge pass: peak/trough marks + compact down list + down out-degree ----
__global__ __launch_bounds__(256) void k_edgeA(const int* __restrict__ ei,
                                               const double* __restrict__ elev64,
                                               unsigned char* __restrict__ notpeak,
                                               unsigned char* __restrict__ nottrough,
                                               int2* __restrict__ down,
                                               int* __restrict__ dcount,
                                               int* __restrict__ odeg, int E) {
    __shared__ int wcnt[4];
    __shared__ int wbase[4];
    int e = blockIdx.x * 256 + threadIdx.x;
    int lane = threadIdx.x & 63, wid = threadIdx.x >> 6;
    int s = 0, d = 0;
    bool le = false;
    if (e < E) {
        s = ei[e];
        d = ei[(size_t)E + e];
        double es = elev64[s], ed = elev64[d];
        if (ed < es) notpeak[d] = 1;    // violates "d >= all neighbors"
        if (ed > es) nottrough[d] = 1;  // violates "d <= all neighbors"
        le = (ed <= es);                // down edge s->d
    }
    if (le) atomicAdd(&odeg[s], 1);
    unsigned long long mk = __ballot(le);
    int rank = __popcll(mk & ((1ull << lane) - 1));
    if (lane == 0) wcnt[wid] = __popcll(mk);
    __syncthreads();
    if (threadIdx.x == 0) {
        int t = wcnt[0] + wcnt[1] + wcnt[2] + wcnt[3];
        int bse = t ? atomicAdd(dcount, t) : 0;
        wbase[0] = bse;
        wbase[1] = bse + wcnt[0];
        wbase[2] = wbase[1] + wcnt[1];
        wbase[3] = wbase[2] + wcnt[2];
    }
    __syncthreads();
    if (le) down[wbase[wid] + rank] = make_int2(s, d);
}

// ---- 3. node pass: flags, best init, seed frontier, per-block peak partials ----
__global__ __launch_bounds__(256) void k_nodes1(const unsigned char* __restrict__ notpeak,
                                                const unsigned char* __restrict__ nottrough,
                                                int* __restrict__ peakflag,
                                                int* __restrict__ best,
                                                float* __restrict__ out_ispeak,
                                                float* __restrict__ out_istrough,
                                                float* __restrict__ out_cb,
                                                int* __restrict__ fcnt,
                                                int* __restrict__ fb0,
                                                int* __restrict__ part, int N) {
    __shared__ int ws[4];
    int n = blockIdx.x * 256 + threadIdx.x;
    int lane = threadIdx.x & 63, wid = threadIdx.x >> 6;
    int pk = 0;
    if (n < N) {
        pk = notpeak[n] ? 0 : 1;
        int tr = nottrough[n] ? 0 : 1;
        peakflag[n] = pk;
        out_ispeak[n] = (float)pk;
        out_istrough[n] = (float)tr;
        best[n] = pk ? n : SENT32;
        out_cb[n] = -1.0f;
    }
    unsigned long long mk = __ballot(pk);
    if (mk) {
        int ldr = __ffsll(mk) - 1;
        int bse = 0;
        if (lane == ldr) bse = atomicAdd(&fcnt[0], __popcll(mk));
        bse = __shfl(bse, ldr, 64);
        if (pk) fb0[bse + __popcll(mk & ((1ull << lane) - 1))] = n;
    }
    if (lane == 0) ws[wid] = __popcll(mk);
    __syncthreads();
    if (threadIdx.x == 0) part[blockIdx.x] = ws[0] + ws[1] + ws[2] + ws[3];
}

// ---- 4. prefix sums ----
__global__ __launch_bounds__(256) void k_scan_part(const int* __restrict__ flag,
                                                   int* __restrict__ part, int N) {
    int n = blockIdx.x * 256 + threadIdx.x;
    int f = (n < N) ? flag[n] : 0;
#pragma unroll
    for (int off = 32; off > 0; off >>= 1) f += __shfl_down(f, off, 64);
    __shared__ int ws[4];
    int lane = threadIdx.x & 63, wid = threadIdx.x >> 6;
    if (lane == 0) ws[wid] = f;
    __syncthreads();
    if (threadIdx.x == 0) part[blockIdx.x] = ws[0] + ws[1] + ws[2] + ws[3];
}

__global__ __launch_bounds__(64) void k_scan_offs(const int* __restrict__ part,
                                                  int* __restrict__ offs, int P) {
    int lane = threadIdx.x;
    int chunk = (P + 63) / 64;
    int s0 = lane * chunk, s1 = min(s0 + chunk, P);
    int s = 0;
    for (int j = s0; j < s1; ++j) s += part[j];
    int incl = s;
#pragma unroll
    for (int off = 1; off < 64; off <<= 1) {
        int t = __shfl_up(incl, off, 64);
        if (lane >= off) incl += t;
    }
    int run = incl - s;
    for (int j = s0; j < s1; ++j) { offs[j] = run; run += part[j]; }
}

// mode 0: out0[n] = inclusive-1; mode 1: out0[n] = out1[n] = exclusive
__global__ __launch_bounds__(256) void k_scan_final(const int* __restrict__ flag,
                                                    const int* __restrict__ offs,
                                                    int* __restrict__ out0,
                                                    int* __restrict__ out1,
                                                    int mode, int N) {
    __shared__ int tmp[256];
    int n = blockIdx.x * 256 + threadIdx.x;
    int f = (n < N) ? flag[n] : 0;
    tmp[threadIdx.x] = f;
    __syncthreads();
    for (int off = 1; off < 256; off <<= 1) {
        int t = (threadIdx.x >= off) ? tmp[threadIdx.x - off] : 0;
        __syncthreads();
        tmp[threadIdx.x] += t;
        __syncthreads();
    }
    if (n < N) {
        int incl = offs[blockIdx.x] + tmp[threadIdx.x];
        if (mode == 0) {
            out0[n] = incl - 1;
        } else {
            int excl = incl - f;
            out0[n] = excl;
            out1[n] = excl;
        }
    }
}

// ---- 4b. CSR adjacency fill from compact down list ----
__global__ __launch_bounds__(256) void k_fill2(const int2* __restrict__ down,
                                               const int* __restrict__ p_nd,
                                               int* __restrict__ cursor,
                                               int* __restrict__ adj) {
    int nd = *p_nd;
    int stride = gridDim.x * blockDim.x;
    for (int i = blockIdx.x * blockDim.x + threadIdx.x; i < nd; i += stride) {
        int2 ed = down[i];
        int pos = atomicAdd(&cursor[ed.x], 1);
        adj[pos] = ed.y;
    }
}

// ---- 5. one BFS level, frontier-driven, sync via kernel boundary ----
// best[v] packs (round<<17)|label; frontier L-1 nodes are settled (kernel
// boundary). atomicMin(best[v], best[u]+2^17) == segment_min over parents
// of round L-1; earlier-assigned nodes reject (smaller packed round).
// First-writer appends v to next frontier exactly once.
__global__ __launch_bounds__(256) void k_level_f(const int* __restrict__ rowptr,
                                                 const int* __restrict__ odeg,
                                                 const int* __restrict__ adj,
                                                 int* __restrict__ best,
                                                 int* __restrict__ fcnt,
                                                 int* __restrict__ fb0,
                                                 int* __restrict__ fb1, int L) {
    int nf = fcnt[L - 1];
    if (nf == 0) return;
    const int* cur = ((L - 1) & 1) ? fb1 : fb0;
    int* nxt = (L & 1) ? fb1 : fb0;
    int stride = gridDim.x * blockDim.x;
    for (int i = blockIdx.x * blockDim.x + threadIdx.x; i < nf; i += stride) {
        int u = cur[i];
        int cand = best[u] + (1 << RSHIFT);
        int a = rowptr[u];
        int m = odeg[u];
        for (int j = 0; j < m; ++j) {
            int v = adj[a + j];
            if (best[v] > cand) {          // stale-safe prefilter
                int old = atomicMin(&best[v], cand);
                if (old == SENT32) {
                    int pos = atomicAdd(&fcnt[L], 1);
                    nxt[pos] = v;
                }
            }
        }
    }
}

// ---- 5b. safety net: frontier BFS for levels beyond NLEVELS, one block ----
__global__ __launch_bounds__(1024) void k_tail_f(const int* __restrict__ rowptr,
                                                 const int* __restrict__ odeg,
                                                 const int* __restrict__ adj,
                                                 int* __restrict__ best,
                                                 int* __restrict__ fcnt,
                                                 int* __restrict__ fb0,
                                                 int* __restrict__ fb1) {
    for (int L = NLEVELS + 1; L < 2000; ++L) {
        if (__hip_atomic_load(&fcnt[L - 1], __ATOMIC_RELAXED,
                              __HIP_MEMORY_SCOPE_AGENT) == 0) return;
        int nf = __hip_atomic_load(&fcnt[L - 1], __ATOMIC_RELAXED,
                                   __HIP_MEMORY_SCOPE_AGENT);
        const int* cur = ((L - 1) & 1) ? fb1 : fb0;
        int* nxt = (L & 1) ? fb1 : fb0;
        for (int i = threadIdx.x; i < nf; i += blockDim.x) {
            int u = __hip_atomic_load(&cur[i], __ATOMIC_RELAXED, __HIP_MEMORY_SCOPE_AGENT);
            int bu = __hip_atomic_load(&best[u], __ATOMIC_RELAXED, __HIP_MEMORY_SCOPE_AGENT);
            int cand = bu + (1 << RSHIFT);
            int a = rowptr[u];
            int m = odeg[u];
            for (int j = 0; j < m; ++j) {
                int v = adj[a + j];
                int pv = __hip_atomic_load(&best[v], __ATOMIC_RELAXED,
                                           __HIP_MEMORY_SCOPE_AGENT);
                if (pv > cand) {
                    int old = atomicMin(&best[v], cand);
                    if (old == SENT32) {
                        int pos = atomicAdd(&fcnt[L], 1);
                        __hip_atomic_store(&nxt[pos], v, __ATOMIC_RELAXED,
                                           __HIP_MEMORY_SCOPE_AGENT);
                    }
                }
            }
        }
        __threadfence();
        __syncthreads();
    }
}

// ---- 6. seg labels, segment max, cluster_batch, cluster histogram ----
__global__ __launch_bounds__(256) void k_seg(const int* __restrict__ best,
                                             const int* __restrict__ new_id,
                                             const float* __restrict__ elev32,
                                             const int* __restrict__ batch,
                                             int* __restrict__ seg,
                                             float* __restrict__ out_seg,
                                             unsigned* __restrict__ segmax,
                                             float* __restrict__ out_cb,
                                             int* __restrict__ hist, int N) {
    int n = blockIdx.x * blockDim.x + threadIdx.x;
    if (n >= N) return;
    int a = best[n];
    int sg = 0;
    if (a != SENT32) {
        sg = new_id[a & IDMASK];
        atomicMax(&segmax[sg], fkey(elev32[n]));
        if ((a >> RSHIFT) == 0) out_cb[sg] = (float)batch[n];  // peak node
    }
    seg[n] = sg;
    out_seg[n] = (float)sg;
    atomicAdd(&hist[sg], 1);
}

// ---- 7. softmax weights + denominator + member-list fill (fused) ----
__global__ __launch_bounds__(256) void k_w_cfill(const int* __restrict__ best,
                                                 const int* __restrict__ seg,
                                                 const float* __restrict__ elev32,
                                                 const unsigned* __restrict__ segmax,
                                                 float* __restrict__ wbuf,
                                                 float* __restrict__ z,
                                                 int* __restrict__ ccursor,
                                                 int* __restrict__ members, int N) {
    int n = blockIdx.x * blockDim.x + threadIdx.x;
    if (n >= N) return;
    int a = best[n];
    int sg = seg[n];
    float wv = 0.0f;
    if (a != SENT32) {
        float smax = funkey(segmax[sg]);
        wv = expf(elev32[n] - smax);
        atomicAdd(&z[sg], wv);
    }
    wbuf[n] = wv;
    int pos = atomicAdd(&ccursor[sg], 1);
    members[pos] = n;
}

// ---- 8. wave-per-cluster pooling (zero atomics); zero-fills rows >= K ----
__global__ __launch_bounds__(256) void k_pool2(const float* __restrict__ x,
                                               const int* __restrict__ members,
                                               const int* __restrict__ cstart,
                                               const int* __restrict__ hist,
                                               const float* __restrict__ wbuf,
                                               const float* __restrict__ z,
                                               const int* __restrict__ p_K,
                                               float* __restrict__ out_scaling,
                                               float* __restrict__ out_pooled,
                                               int N, int C) {
    int lane = threadIdx.x & 63;
    int w = blockIdx.x * (blockDim.x >> 6) + (threadIdx.x >> 6);
    int nw = gridDim.x * (blockDim.x >> 6);
    int K = *p_K;
    int c1 = lane + 64;
    for (int cl = w; cl < N; cl += nw) {
        float* pr = out_pooled + (size_t)cl * C;
        if (cl >= K) {           // zero padding rows
            pr[lane] = 0.0f;
            if (c1 < C) pr[c1] = 0.0f;
            continue;
        }
        int s0 = cstart[cl], cnt = hist[cl];
        float zz = z[cl] + 1e-12f;
        float a0 = 0.0f, a1 = 0.0f;
        for (int j = 0; j < cnt; ++j) {
            int m = members[s0 + j];
            float sc = wbuf[m] / zz;
            const float* xr = x + (size_t)m * C;
            a0 += xr[lane] * sc;
            if (c1 < C) a1 += xr[c1] * sc;
            if (lane == 0) out_scaling[m] = sc;
        }
        pr[lane] = a0;
        if (c1 < C) pr[c1] = a1;
    }
}

extern "C" void kernel_launch(void* const* d_in, const int* in_sizes, int n_in,
                              void* d_out, int out_size, void* d_ws, size_t ws_size,
                              hipStream_t stream) {
    const float* x = (const float*)d_in[0];
    const float* W = (const float*)d_in[1];
    const float* b = (const float*)d_in[2];
    const int* ei = (const int*)d_in[3];
    const int* batch = (const int*)d_in[4];

    const int C = in_sizes[1];           // 128
    const int N = in_sizes[0] / C;       // 100000
    const int E = in_sizes[3] / 2;       // 3200000

    float* out_pooled   = (float*)d_out;
    float* out_seg      = out_pooled + (size_t)N * C;
    float* out_scaling  = out_seg + N;
    float* out_cb       = out_scaling + N;
    float* out_ispeak   = out_cb + N;
    float* out_istrough = out_ispeak + N;

    char* p = (char*)d_ws;
    auto alloc = [&](size_t bytes) -> char* {
        char* r = p;
        p += (bytes + 255) & ~(size_t)255;
        return r;
    };
    double* elev64 = (double*)alloc((size_t)N * 8);
    float* elev32  = (float*)alloc((size_t)N * 4);
    int* best      = (int*)alloc((size_t)N * 4);
    int* peakflag  = (int*)alloc((size_t)N * 4);
    int* new_id    = (int*)alloc((size_t)N * 4);
    int* seg       = (int*)alloc((size_t)N * 4);
    float* wbuf    = (float*)alloc((size_t)N * 4);
    int* rowptr    = (int*)alloc((size_t)N * 4);
    int* cursor    = (int*)alloc((size_t)N * 4);
    int* members   = (int*)alloc((size_t)N * 4);
    int* cstart    = (int*)alloc((size_t)N * 4);
    int* ccursor   = (int*)alloc((size_t)N * 4);
    int* fb0       = (int*)alloc((size_t)N * 4);
    int* fb1       = (int*)alloc((size_t)N * 4);
    const int P = (N + 255) / 256;
    int* part = (int*)alloc((size_t)P * 4);
    int* offs = (int*)alloc((size_t)P * 4);
    char* zbeg = p;  // zero-initialized region starts here
    unsigned char* notpeak   = (unsigned char*)alloc((size_t)N);
    unsigned char* nottrough = (unsigned char*)alloc((size_t)N);
    unsigned* segmax = (unsigned*)alloc((size_t)N * 4);
    float* z         = (float*)alloc((size_t)N * 4);
    int* hist        = (int*)alloc((size_t)N * 4);
    int* odeg        = (int*)alloc((size_t)N * 4);
    int* fcnt        = (int*)alloc(2048 * 4);
    int* dcount      = (int*)alloc(256);
    size_t zspan = (size_t)(p - zbeg);
    int2* down = (int2*)alloc((size_t)E * 8);
    int* adj   = (int*)alloc((size_t)E * 4);
    (void)ws_size;

    hipMemsetAsync(zbeg, 0, zspan, stream);

    k_matvec<<<(N + 3) / 4, 256, 0, stream>>>(x, W, b, elev64, elev32, N, C);
    k_edgeA<<<(E + 255) / 256, 256, 0, stream>>>(ei, elev64, notpeak, nottrough,
                                                 down, dcount, odeg, E);
    k_nodes1<<<P, 256, 0, stream>>>(notpeak, nottrough, peakflag, best,
                                    out_ispeak, out_istrough, out_cb,
                                    fcnt, fb0, part, N);
    // new_id = inclusive_scan(peakflag) - 1  (partials already in part)
    k_scan_offs<<<1, 64, 0, stream>>>(part, offs, P);
    k_scan_final<<<P, 256, 0, stream>>>(peakflag, offs, new_id, nullptr, 0, N);
    // rowptr/cursor = exclusive_scan(odeg)
    k_scan_part<<<P, 256, 0, stream>>>(odeg, part, N);
    k_scan_offs<<<1, 64, 0, stream>>>(part, offs, P);
    k_scan_final<<<P, 256, 0, stream>>>(odeg, offs, rowptr, cursor, 1, N);
    k_fill2<<<2048, 256, 0, stream>>>(down, dcount, cursor, adj);

    // frontier BFS: kernel-boundary-synchronized levels
    for (int L = 1; L <= NLEVELS; ++L)
        k_level_f<<<256, 256, 0, stream>>>(rowptr, odeg, adj, best, fcnt, fb0, fb1, L);
    k_tail_f<<<1, 1024, 0, stream>>>(rowptr, odeg, adj, best, fcnt, fb0, fb1);

    k_seg<<<(N + 255) / 256, 256, 0, stream>>>(best, new_id, elev32, batch, seg,
                                               out_seg, segmax, out_cb, hist, N);
    // cstart/ccursor = exclusive_scan(hist)
    k_scan_part<<<P, 256, 0, stream>>>(hist, part, N);
    k_scan_offs<<<1, 64, 0, stream>>>(part, offs, P);
    k_scan_final<<<P, 256, 0, stream>>>(hist, offs, cstart, ccursor, 1, N);

    k_w_cfill<<<(N + 255) / 256, 256, 0, stream>>>(best, seg, elev32, segmax,
                                                   wbuf, z, ccursor, members, N);
    k_pool2<<<512, 256, 0, stream>>>(x, members, cstart, hist, wbuf, z,
                                     fcnt, out_scaling, out_pooled, N, C);
}

// Round 7
// 755.109 us; speedup vs baseline: 1.3430x; 1.3430x over previous
//
#include <hip/hip_runtime.h>

#define SENT32 0x7FFFFFFF
#define IDMASK 0x1FFFF
#define RSHIFT 17
#define NLEVELS 12

__device__ __forceinline__ unsigned fkey(float f) {
    unsigned u = __float_as_uint(f);
    return (u & 0x80000000u) ? ~u : (u | 0x80000000u);
}
__device__ __forceinline__ float funkey(unsigned k) {
    unsigned u = (k & 0x80000000u) ? (k & 0x7FFFFFFFu) : ~k;
    return __uint_as_float(u);
}

// ---- 1. elevation: elev = x @ W + b, f64 accumulation, wave-per-row ----
__global__ __launch_bounds__(256) void k_matvec(const float* __restrict__ x,
                                                const float* __restrict__ W,
                                                const float* __restrict__ b,
                                                double* __restrict__ elev64,
                                                float* __restrict__ elev32,
                                                int N, int C) {
    int lane = threadIdx.x & 63;
    int wib  = threadIdx.x >> 6;
    int row  = blockIdx.x * (blockDim.x >> 6) + wib;
    if (row >= N) return;
    const float* xr = x + (size_t)row * C;
    double s = 0.0;
    for (int c = lane; c < C; c += 64) s += (double)xr[c] * (double)W[c];
#pragma unroll
    for (int off = 32; off > 0; off >>= 1) s += __shfl_down(s, off, 64);
    if (lane == 0) {
        double v = s + (double)b[0];
        elev64[row] = v;
        elev32[row] = (float)v;
    }
}

// ---- 2. edge pass over UNDIRECTED pairs (input is [src||dst ; dst||src]):
// pair e<E/2 covers directed edges (s,d) and (d,s). Peak/trough violation
// marks + compact down-edge list (both directions) + down out-degrees. ----
__global__ __launch_bounds__(256) void k_edgeA(const int* __restrict__ ei,
                                               const double* __restrict__ elev64,
                                               unsigned char* __restrict__ notpeak,
                                               unsigned char* __restrict__ nottrough,
                                               int2* __restrict__ down,
                                               int* __restrict__ dcount,
                                               int* __restrict__ odeg, int Eh, int E) {
    __shared__ int wcnt[4];
    __shared__ int wbase[4];
    int e = blockIdx.x * 256 + threadIdx.x;
    int lane = threadIdx.x & 63, wid = threadIdx.x >> 6;
    int s = 0, d = 0;
    bool le_sd = false, le_ds = false;
    if (e < Eh) {
        s = ei[e];
        d = ei[(size_t)E + e];
        double es = elev64[s], ed = elev64[d];
        if (ed < es)      { notpeak[d] = 1; nottrough[s] = 1; }
        else if (ed > es) { notpeak[s] = 1; nottrough[d] = 1; }
        le_sd = (ed <= es);   // down edge s->d
        le_ds = (es <= ed);   // down edge d->s
        if (le_sd) atomicAdd(&odeg[s], 1);
        if (le_ds) atomicAdd(&odeg[d], 1);
    }
    int cnt = (int)le_sd + (int)le_ds;
    int pfx = cnt;
#pragma unroll
    for (int off = 1; off < 64; off <<= 1) {
        int t = __shfl_up(pfx, off, 64);
        if (lane >= off) pfx += t;
    }
    if (lane == 63) wcnt[wid] = pfx;
    __syncthreads();
    if (threadIdx.x == 0) {
        int t = wcnt[0] + wcnt[1] + wcnt[2] + wcnt[3];
        int bse = t ? atomicAdd(dcount, t) : 0;
        wbase[0] = bse;
        wbase[1] = bse + wcnt[0];
        wbase[2] = wbase[1] + wcnt[1];
        wbase[3] = wbase[2] + wcnt[2];
    }
    __syncthreads();
    int p0 = wbase[wid] + pfx - cnt;
    if (le_sd) down[p0++] = make_int2(s, d);
    if (le_ds) down[p0] = make_int2(d, s);
}

// ---- 3. node pass: flags, best init, seed frontier, per-block peak partials ----
__global__ __launch_bounds__(256) void k_nodes1(const unsigned char* __restrict__ notpeak,
                                                const unsigned char* __restrict__ nottrough,
                                                int* __restrict__ peakflag,
                                                int* __restrict__ best,
                                                float* __restrict__ out_ispeak,
                                                float* __restrict__ out_istrough,
                                                float* __restrict__ out_cb,
                                                int* __restrict__ fcnt,
                                                int* __restrict__ fb0,
                                                int* __restrict__ part, int N) {
    __shared__ int ws[4];
    int n = blockIdx.x * 256 + threadIdx.x;
    int lane = threadIdx.x & 63, wid = threadIdx.x >> 6;
    int pk = 0;
    if (n < N) {
        pk = notpeak[n] ? 0 : 1;
        int tr = nottrough[n] ? 0 : 1;
        peakflag[n] = pk;
        out_ispeak[n] = (float)pk;
        out_istrough[n] = (float)tr;
        best[n] = pk ? n : SENT32;
        out_cb[n] = -1.0f;
    }
    unsigned long long mk = __ballot(pk);
    if (mk) {
        int ldr = __ffsll(mk) - 1;
        int bse = 0;
        if (lane == ldr) bse = atomicAdd(&fcnt[0], __popcll(mk));
        bse = __shfl(bse, ldr, 64);
        if (pk) fb0[bse + __popcll(mk & ((1ull << lane) - 1))] = n;
    }
    if (lane == 0) ws[wid] = __popcll(mk);
    __syncthreads();
    if (threadIdx.x == 0) part[blockIdx.x] = ws[0] + ws[1] + ws[2] + ws[3];
}

// ---- 4. prefix sums ----
__global__ __launch_bounds__(256) void k_scan_part(const int* __restrict__ flag,
                                                   int* __restrict__ part, int N) {
    int n = blockIdx.x * 256 + threadIdx.x;
    int f = (n < N) ? flag[n] : 0;
#pragma unroll
    for (int off = 32; off > 0; off >>= 1) f += __shfl_down(f, off, 64);
    __shared__ int ws[4];
    int lane = threadIdx.x & 63, wid = threadIdx.x >> 6;
    if (lane == 0) ws[wid] = f;
    __syncthreads();
    if (threadIdx.x == 0) part[blockIdx.x] = ws[0] + ws[1] + ws[2] + ws[3];
}

__global__ __launch_bounds__(64) void k_scan_offs(const int* __restrict__ part,
                                                  int* __restrict__ offs, int P) {
    int lane = threadIdx.x;
    int chunk = (P + 63) / 64;
    int s0 = lane * chunk, s1 = min(s0 + chunk, P);
    int s = 0;
    for (int j = s0; j < s1; ++j) s += part[j];
    int incl = s;
#pragma unroll
    for (int off = 1; off < 64; off <<= 1) {
        int t = __shfl_up(incl, off, 64);
        if (lane >= off) incl += t;
    }
    int run = incl - s;
    for (int j = s0; j < s1; ++j) { offs[j] = run; run += part[j]; }
}

// mode 0: out0[n] = inclusive-1; mode 1: out0[n] = out1[n] = exclusive
__global__ __launch_bounds__(256) void k_scan_final(const int* __restrict__ flag,
                                                    const int* __restrict__ offs,
                                                    int* __restrict__ out0,
                                                    int* __restrict__ out1,
                                                    int mode, int N) {
    __shared__ int tmp[256];
    int n = blockIdx.x * 256 + threadIdx.x;
    int f = (n < N) ? flag[n] : 0;
    tmp[threadIdx.x] = f;
    __syncthreads();
    for (int off = 1; off < 256; off <<= 1) {
        int t = (threadIdx.x >= off) ? tmp[threadIdx.x - off] : 0;
        __syncthreads();
        tmp[threadIdx.x] += t;
        __syncthreads();
    }
    if (n < N) {
        int incl = offs[blockIdx.x] + tmp[threadIdx.x];
        if (mode == 0) {
            out0[n] = incl - 1;
        } else {
            int excl = incl - f;
            out0[n] = excl;
            out1[n] = excl;
        }
    }
}

// ---- 4b. CSR adjacency fill from compact down list ----
__global__ __launch_bounds__(256) void k_fill2(const int2* __restrict__ down,
                                               const int* __restrict__ p_nd,
                                               int* __restrict__ cursor,
                                               int* __restrict__ adj) {
    int nd = *p_nd;
    int stride = gridDim.x * blockDim.x;
    for (int i = blockIdx.x * blockDim.x + threadIdx.x; i < nd; i += stride) {
        int2 ed = down[i];
        int pos = atomicAdd(&cursor[ed.x], 1);
        adj[pos] = ed.y;
    }
}

// ---- 5. one BFS level, frontier-driven, sync via kernel boundary ----
__global__ __launch_bounds__(256) void k_level_f(const int* __restrict__ rowptr,
                                                 const int* __restrict__ odeg,
                                                 const int* __restrict__ adj,
                                                 int* __restrict__ best,
                                                 int* __restrict__ fcnt,
                                                 int* __restrict__ fb0,
                                                 int* __restrict__ fb1, int L) {
    int nf = fcnt[L - 1];
    if (nf == 0) return;
    const int* cur = ((L - 1) & 1) ? fb1 : fb0;
    int* nxt = (L & 1) ? fb1 : fb0;
    int stride = gridDim.x * blockDim.x;
    for (int i = blockIdx.x * blockDim.x + threadIdx.x; i < nf; i += stride) {
        int u = cur[i];
        int cand = best[u] + (1 << RSHIFT);
        int a = rowptr[u];
        int m = odeg[u];
        for (int j = 0; j < m; ++j) {
            int v = adj[a + j];
            if (best[v] > cand) {          // stale-safe prefilter
                int old = atomicMin(&best[v], cand);
                if (old == SENT32) {
                    int pos = atomicAdd(&fcnt[L], 1);
                    nxt[pos] = v;
                }
            }
        }
    }
}

// ---- 5b. safety net: frontier BFS for levels beyond NLEVELS, one block ----
__global__ __launch_bounds__(1024) void k_tail_f(const int* __restrict__ rowptr,
                                                 const int* __restrict__ odeg,
                                                 const int* __restrict__ adj,
                                                 int* __restrict__ best,
                                                 int* __restrict__ fcnt,
                                                 int* __restrict__ fb0,
                                                 int* __restrict__ fb1) {
    for (int L = NLEVELS + 1; L < 2000; ++L) {
        int nf = __hip_atomic_load(&fcnt[L - 1], __ATOMIC_RELAXED,
                                   __HIP_MEMORY_SCOPE_AGENT);
        if (nf == 0) return;
        const int* cur = ((L - 1) & 1) ? fb1 : fb0;
        int* nxt = (L & 1) ? fb1 : fb0;
        for (int i = threadIdx.x; i < nf; i += blockDim.x) {
            int u = __hip_atomic_load(&cur[i], __ATOMIC_RELAXED, __HIP_MEMORY_SCOPE_AGENT);
            int bu = __hip_atomic_load(&best[u], __ATOMIC_RELAXED, __HIP_MEMORY_SCOPE_AGENT);
            int cand = bu + (1 << RSHIFT);
            int a = rowptr[u];
            int m = odeg[u];
            for (int j = 0; j < m; ++j) {
                int v = adj[a + j];
                int pv = __hip_atomic_load(&best[v], __ATOMIC_RELAXED,
                                           __HIP_MEMORY_SCOPE_AGENT);
                if (pv > cand) {
                    int old = atomicMin(&best[v], cand);
                    if (old == SENT32) {
                        int pos = atomicAdd(&fcnt[L], 1);
                        __hip_atomic_store(&nxt[pos], v, __ATOMIC_RELAXED,
                                           __HIP_MEMORY_SCOPE_AGENT);
                    }
                }
            }
        }
        __threadfence();
        __syncthreads();
    }
}

// ---- 6. seg labels, segment max, cluster_batch scatter ----
__global__ __launch_bounds__(256) void k_seg(const int* __restrict__ best,
                                             const int* __restrict__ new_id,
                                             const float* __restrict__ elev32,
                                             const int* __restrict__ batch,
                                             int* __restrict__ seg,
                                             float* __restrict__ out_seg,
                                             unsigned* __restrict__ segmax,
                                             float* __restrict__ out_cb, int N) {
    int n = blockIdx.x * blockDim.x + threadIdx.x;
    if (n >= N) return;
    int a = best[n];
    int sg = 0;
    if (a != SENT32) {
        sg = new_id[a & IDMASK];
        atomicMax(&segmax[sg], fkey(elev32[n]));
        if ((a >> RSHIFT) == 0) out_cb[sg] = (float)batch[n];  // peak node
    }
    seg[n] = sg;
    out_seg[n] = (float)sg;
}

// ---- 7. softmax weights + denominator ----
__global__ __launch_bounds__(256) void k_w(const int* __restrict__ best,
                                           const int* __restrict__ seg,
                                           const float* __restrict__ elev32,
                                           const unsigned* __restrict__ segmax,
                                           float* __restrict__ wbuf,
                                           float* __restrict__ z, int N) {
    int n = blockIdx.x * blockDim.x + threadIdx.x;
    if (n >= N) return;
    int a = best[n];
    int sg = seg[n];
    float wv = 0.0f;
    if (a != SENT32) {
        float smax = funkey(segmax[sg]);
        wv = expf(elev32[n] - smax);
        atomicAdd(&z[sg], wv);
    }
    wbuf[n] = wv;
}

// ---- 8. scaling + weighted pooling (wave-per-node, L2-side atomics) ----
__global__ __launch_bounds__(256) void k_pool(const float* __restrict__ x,
                                              const int* __restrict__ seg,
                                              const float* __restrict__ wbuf,
                                              const float* __restrict__ z,
                                              float* __restrict__ out_scaling,
                                              float* __restrict__ out_pooled,
                                              int N, int C) {
    int lane = threadIdx.x & 63;
    int node = blockIdx.x * (blockDim.x >> 6) + (threadIdx.x >> 6);
    if (node >= N) return;
    int sg = seg[node];
    float sc = wbuf[node] / (z[sg] + 1e-12f);
    if (lane == 0) out_scaling[node] = sc;
    const float* xr = x + (size_t)node * C;
    float* pr = out_pooled + (size_t)sg * C;
    for (int c = lane; c < C; c += 64) atomicAdd(&pr[c], xr[c] * sc);
}

extern "C" void kernel_launch(void* const* d_in, const int* in_sizes, int n_in,
                              void* d_out, int out_size, void* d_ws, size_t ws_size,
                              hipStream_t stream) {
    const float* x = (const float*)d_in[0];
    const float* W = (const float*)d_in[1];
    const float* b = (const float*)d_in[2];
    const int* ei = (const int*)d_in[3];
    const int* batch = (const int*)d_in[4];

    const int C = in_sizes[1];           // 128
    const int N = in_sizes[0] / C;       // 100000
    const int E = in_sizes[3] / 2;       // 3200000
    const int Eh = E / 2;                // 1600000 undirected pairs

    float* out_pooled   = (float*)d_out;
    float* out_seg      = out_pooled + (size_t)N * C;
    float* out_scaling  = out_seg + N;
    float* out_cb       = out_scaling + N;
    float* out_ispeak   = out_cb + N;
    float* out_istrough = out_ispeak + N;

    char* p = (char*)d_ws;
    auto alloc = [&](size_t bytes) -> char* {
        char* r = p;
        p += (bytes + 255) & ~(size_t)255;
        return r;
    };
    double* elev64 = (double*)alloc((size_t)N * 8);
    float* elev32  = (float*)alloc((size_t)N * 4);
    int* best      = (int*)alloc((size_t)N * 4);
    int* peakflag  = (int*)alloc((size_t)N * 4);
    int* new_id    = (int*)alloc((size_t)N * 4);
    int* seg       = (int*)alloc((size_t)N * 4);
    float* wbuf    = (float*)alloc((size_t)N * 4);
    int* rowptr    = (int*)alloc((size_t)N * 4);
    int* cursor    = (int*)alloc((size_t)N * 4);
    int* fb0       = (int*)alloc((size_t)N * 4);
    int* fb1       = (int*)alloc((size_t)N * 4);
    const int P = (N + 255) / 256;
    int* part = (int*)alloc((size_t)P * 4);
    int* offs = (int*)alloc((size_t)P * 4);
    char* zbeg = p;  // zero-initialized region starts here
    unsigned char* notpeak   = (unsigned char*)alloc((size_t)N);
    unsigned char* nottrough = (unsigned char*)alloc((size_t)N);
    unsigned* segmax = (unsigned*)alloc((size_t)N * 4);
    float* z         = (float*)alloc((size_t)N * 4);
    int* odeg        = (int*)alloc((size_t)N * 4);
    int* fcnt        = (int*)alloc(2048 * 4);
    int* dcount      = (int*)alloc(256);
    size_t zspan = (size_t)(p - zbeg);
    int2* down = (int2*)alloc((size_t)E * 8);
    int* adj   = (int*)alloc((size_t)E * 4);
    (void)ws_size;

    hipMemsetAsync(zbeg, 0, zspan, stream);
    hipMemsetAsync(out_pooled, 0, (size_t)N * C * sizeof(float), stream);

    k_matvec<<<(N + 3) / 4, 256, 0, stream>>>(x, W, b, elev64, elev32, N, C);
    k_edgeA<<<(Eh + 255) / 256, 256, 0, stream>>>(ei, elev64, notpeak, nottrough,
                                                  down, dcount, odeg, Eh, E);
    k_nodes1<<<P, 256, 0, stream>>>(notpeak, nottrough, peakflag, best,
                                    out_ispeak, out_istrough, out_cb,
                                    fcnt, fb0, part, N);
    // new_id = inclusive_scan(peakflag) - 1  (partials already in part)
    k_scan_offs<<<1, 64, 0, stream>>>(part, offs, P);
    k_scan_final<<<P, 256, 0, stream>>>(peakflag, offs, new_id, nullptr, 0, N);
    // rowptr/cursor = exclusive_scan(odeg)
    k_scan_part<<<P, 256, 0, stream>>>(odeg, part, N);
    k_scan_offs<<<1, 64, 0, stream>>>(part, offs, P);
    k_scan_final<<<P, 256, 0, stream>>>(odeg, offs, rowptr, cursor, 1, N);
    k_fill2<<<2048, 256, 0, stream>>>(down, dcount, cursor, adj);

    // frontier BFS: kernel-boundary-synchronized levels
    for (int L = 1; L <= NLEVELS; ++L)
        k_level_f<<<256, 256, 0, stream>>>(rowptr, odeg, adj, best, fcnt, fb0, fb1, L);
    k_tail_f<<<1, 1024, 0, stream>>>(rowptr, odeg, adj, best, fcnt, fb0, fb1);

    k_seg<<<(N + 255) / 256, 256, 0, stream>>>(best, new_id, elev32, batch, seg,
                                               out_seg, segmax, out_cb, N);
    k_w<<<(N + 255) / 256, 256, 0, stream>>>(best, seg, elev32, segmax, wbuf, z, N);
    k_pool<<<(N + 3) / 4, 256, 0, stream>>>(x, seg, wbuf, z, out_scaling,
                                            out_pooled, N, C);
}

// Round 8
// 359.786 us; speedup vs baseline: 2.8187x; 2.0988x over previous
//
#include <hip/hip_runtime.h>

#define SENT32 0x7FFFFFFF
#define IDMASK 0x1FFFF
#define RSHIFT 17
#define NLEVELS 10

// ---- 1. elevation: elev = x @ W + b, f64 accumulation, wave-per-row ----
__global__ __launch_bounds__(256) void k_matvec(const float* __restrict__ x,
                                                const float* __restrict__ W,
                                                const float* __restrict__ b,
                                                double* __restrict__ elev64,
                                                float* __restrict__ elev32,
                                                int N, int C) {
    int lane = threadIdx.x & 63;
    int wib  = threadIdx.x >> 6;
    int row  = blockIdx.x * (blockDim.x >> 6) + wib;
    if (row >= N) return;
    const float* xr = x + (size_t)row * C;
    double s = 0.0;
    for (int c = lane; c < C; c += 64) s += (double)xr[c] * (double)W[c];
#pragma unroll
    for (int off = 32; off > 0; off >>= 1) s += __shfl_down(s, off, 64);
    if (lane == 0) {
        double v = s + (double)b[0];
        elev64[row] = v;
        elev32[row] = (float)v;
    }
}

// ---- 2. edge pass over UNDIRECTED pairs (input is [src||dst ; dst||src]):
// peak/trough violation marks + compact down-edge list (both directions). ----
__global__ __launch_bounds__(256) void k_edgeA(const int* __restrict__ ei,
                                               const double* __restrict__ elev64,
                                               unsigned char* __restrict__ notpeak,
                                               unsigned char* __restrict__ nottrough,
                                               int2* __restrict__ down,
                                               int* __restrict__ dcnt, int Eh, int E) {
    __shared__ int wcnt[4];
    __shared__ int wbase[4];
    int e = blockIdx.x * 256 + threadIdx.x;
    int lane = threadIdx.x & 63, wid = threadIdx.x >> 6;
    int s = 0, d = 0;
    bool le_sd = false, le_ds = false;
    if (e < Eh) {
        s = ei[e];
        d = ei[(size_t)E + e];
        double es = elev64[s], ed = elev64[d];
        if (ed < es)      { notpeak[d] = 1; nottrough[s] = 1; }
        else if (ed > es) { notpeak[s] = 1; nottrough[d] = 1; }
        le_sd = (ed <= es);   // down edge s->d
        le_ds = (es <= ed);   // down edge d->s
    }
    int cnt = (int)le_sd + (int)le_ds;
    int pfx = cnt;
#pragma unroll
    for (int off = 1; off < 64; off <<= 1) {
        int t = __shfl_up(pfx, off, 64);
        if (lane >= off) pfx += t;
    }
    if (lane == 63) wcnt[wid] = pfx;
    __syncthreads();
    if (threadIdx.x == 0) {
        int t = wcnt[0] + wcnt[1] + wcnt[2] + wcnt[3];
        int bse = t ? atomicAdd(&dcnt[0], t) : 0;
        wbase[0] = bse;
        wbase[1] = bse + wcnt[0];
        wbase[2] = wbase[1] + wcnt[1];
        wbase[3] = wbase[2] + wcnt[2];
    }
    __syncthreads();
    int p0 = wbase[wid] + pfx - cnt;
    if (le_sd) down[p0++] = make_int2(s, d);
    if (le_ds) down[p0] = make_int2(d, s);
}

// ---- 3. node pass: flags, best init, per-block peak partials ----
__global__ __launch_bounds__(256) void k_nodes1(const unsigned char* __restrict__ notpeak,
                                                const unsigned char* __restrict__ nottrough,
                                                int* __restrict__ peakflag,
                                                int* __restrict__ best,
                                                float* __restrict__ out_ispeak,
                                                float* __restrict__ out_istrough,
                                                float* __restrict__ out_cb,
                                                int* __restrict__ part, int N) {
    __shared__ int ws[4];
    int n = blockIdx.x * 256 + threadIdx.x;
    int lane = threadIdx.x & 63, wid = threadIdx.x >> 6;
    int pk = 0;
    if (n < N) {
        pk = notpeak[n] ? 0 : 1;
        int tr = nottrough[n] ? 0 : 1;
        peakflag[n] = pk;
        out_ispeak[n] = (float)pk;
        out_istrough[n] = (float)tr;
        best[n] = pk ? n : SENT32;
        out_cb[n] = -1.0f;
    }
    unsigned long long mk = __ballot(pk);
    if (lane == 0) ws[wid] = __popcll(mk);
    __syncthreads();
    if (threadIdx.x == 0) part[blockIdx.x] = ws[0] + ws[1] + ws[2] + ws[3];
}

// ---- 4. prefix sums (for new_id only) ----
__global__ __launch_bounds__(64) void k_scan_offs(const int* __restrict__ part,
                                                  int* __restrict__ offs, int P) {
    int lane = threadIdx.x;
    int chunk = (P + 63) / 64;
    int s0 = lane * chunk, s1 = min(s0 + chunk, P);
    int s = 0;
    for (int j = s0; j < s1; ++j) s += part[j];
    int incl = s;
#pragma unroll
    for (int off = 1; off < 64; off <<= 1) {
        int t = __shfl_up(incl, off, 64);
        if (lane >= off) incl += t;
    }
    int run = incl - s;
    for (int j = s0; j < s1; ++j) { offs[j] = run; run += part[j]; }
}

__global__ __launch_bounds__(256) void k_scan_final(const int* __restrict__ flag,
                                                    const int* __restrict__ offs,
                                                    int* __restrict__ out0, int N) {
    __shared__ int tmp[256];
    int n = blockIdx.x * 256 + threadIdx.x;
    int f = (n < N) ? flag[n] : 0;
    tmp[threadIdx.x] = f;
    __syncthreads();
    for (int off = 1; off < 256; off <<= 1) {
        int t = (threadIdx.x >= off) ? tmp[threadIdx.x - off] : 0;
        __syncthreads();
        tmp[threadIdx.x] += t;
        __syncthreads();
    }
    if (n < N) out0[n] = offs[blockIdx.x] + tmp[threadIdx.x] - 1;  // new_id
}

// ---- 5. one BFS level: edge-centric over shrinking compacted list ----
// best[v] packs (round<<17)|label, monotone decreasing => stale reads are
// always >= actual, every race case safe. Per edge at level L:
//   round(best[src])==L-1 -> relax (atomicMin) and drop
//   else dst assigned      -> drop (future cand round > dst round, useless)
//   else                   -> keep (block-aggregated contiguous append)
__global__ __launch_bounds__(256) void k_level_e(int2* __restrict__ d0,
                                                 int2* __restrict__ d1,
                                                 int* __restrict__ dcnt,
                                                 int* __restrict__ best, int L) {
    int ne = dcnt[L - 1];
    if (ne == 0) return;
    const int2* src = ((L - 1) & 1) ? d1 : d0;
    int2* dst = (L & 1) ? d1 : d0;
    __shared__ int wcnt[4];
    __shared__ int wbase[4];
    int lane = threadIdx.x & 63, wid = threadIdx.x >> 6;
    int stride = gridDim.x * 256;
    for (int base = blockIdx.x * 256; base < ne; base += stride) {
        int i = base + threadIdx.x;
        int2 ed = make_int2(0, 0);
        bool keep = false;
        if (i < ne) {
            ed = src[i];
            int bs = best[ed.x];
            if ((bs >> RSHIFT) == L - 1) {
                int cand = bs + (1 << RSHIFT);
                if (best[ed.y] > cand) atomicMin(&best[ed.y], cand);
            } else {
                keep = (best[ed.y] == SENT32);
            }
        }
        int c = keep ? 1 : 0, pfx = c;
#pragma unroll
        for (int off = 1; off < 64; off <<= 1) {
            int t = __shfl_up(pfx, off, 64);
            if (lane >= off) pfx += t;
        }
        if (lane == 63) wcnt[wid] = pfx;
        __syncthreads();
        if (threadIdx.x == 0) {
            int t = wcnt[0] + wcnt[1] + wcnt[2] + wcnt[3];
            int bse = t ? atomicAdd(&dcnt[L], t) : 0;
            wbase[0] = bse;
            wbase[1] = bse + wcnt[0];
            wbase[2] = wbase[1] + wcnt[1];
            wbase[3] = wbase[2] + wcnt[2];
        }
        __syncthreads();
        if (keep) dst[wbase[wid] + pfx - 1] = ed;
        __syncthreads();  // wcnt/wbase reused next iteration
    }
}

// ---- 5b. safety net: levels beyond NLEVELS, single block ----
__global__ __launch_bounds__(1024) void k_tail_e(int2* __restrict__ d0,
                                                 int2* __restrict__ d1,
                                                 int* __restrict__ dcnt,
                                                 int* __restrict__ best) {
    for (int L = NLEVELS + 1; L < 2000; ++L) {
        int ne = dcnt[L - 1];
        if (ne == 0) return;
        const int2* src = ((L - 1) & 1) ? d1 : d0;
        int2* dst = (L & 1) ? d1 : d0;
        for (int i = threadIdx.x; i < ne; i += blockDim.x) {
            int2 ed = src[i];
            int bs = best[ed.x];
            if ((bs >> RSHIFT) == L - 1) {
                int cand = bs + (1 << RSHIFT);
                if (best[ed.y] > cand) atomicMin(&best[ed.y], cand);
            } else if (best[ed.y] == SENT32) {
                int pos = atomicAdd(&dcnt[L], 1);
                dst[pos] = ed;
            }
        }
        __threadfence();
        __syncthreads();
    }
}

// ---- 6. fused: seg labels + cluster_batch + softmax weight + z.
// segmax[cluster] == elev32[peak] (watershed paths are non-increasing),
// so no segment-max pass is needed: smax = elev32[best[n] & IDMASK]. ----
__global__ __launch_bounds__(256) void k_segw(const int* __restrict__ best,
                                              const int* __restrict__ new_id,
                                              const float* __restrict__ elev32,
                                              const int* __restrict__ batch,
                                              int* __restrict__ seg,
                                              float* __restrict__ out_seg,
                                              float* __restrict__ out_cb,
                                              float* __restrict__ wbuf,
                                              float* __restrict__ z, int N) {
    int n = blockIdx.x * blockDim.x + threadIdx.x;
    if (n >= N) return;
    int a = best[n];
    int sg = 0;
    float wv = 0.0f;
    if (a != SENT32) {
        int pk = a & IDMASK;              // originating peak node id
        sg = new_id[pk];
        if ((a >> RSHIFT) == 0) out_cb[sg] = (float)batch[n];  // peak node
        wv = expf(elev32[n] - elev32[pk]);
        atomicAdd(&z[sg], wv);
    }
    seg[n] = sg;
    out_seg[n] = (float)sg;
    wbuf[n] = wv;
}

// ---- 7. scaling + weighted pooling (wave-per-node, L2-side atomics) ----
__global__ __launch_bounds__(256) void k_pool(const float* __restrict__ x,
                                              const int* __restrict__ seg,
                                              const float* __restrict__ wbuf,
                                              const float* __restrict__ z,
                                              float* __restrict__ out_scaling,
                                              float* __restrict__ out_pooled,
                                              int N, int C) {
    int lane = threadIdx.x & 63;
    int node = blockIdx.x * (blockDim.x >> 6) + (threadIdx.x >> 6);
    if (node >= N) return;
    int sg = seg[node];
    float sc = wbuf[node] / (z[sg] + 1e-12f);
    if (lane == 0) out_scaling[node] = sc;
    const float* xr = x + (size_t)node * C;
    float* pr = out_pooled + (size_t)sg * C;
    for (int c = lane; c < C; c += 64) atomicAdd(&pr[c], xr[c] * sc);
}

extern "C" void kernel_launch(void* const* d_in, const int* in_sizes, int n_in,
                              void* d_out, int out_size, void* d_ws, size_t ws_size,
                              hipStream_t stream) {
    const float* x = (const float*)d_in[0];
    const float* W = (const float*)d_in[1];
    const float* b = (const float*)d_in[2];
    const int* ei = (const int*)d_in[3];
    const int* batch = (const int*)d_in[4];

    const int C = in_sizes[1];           // 128
    const int N = in_sizes[0] / C;       // 100000
    const int E = in_sizes[3] / 2;       // 3200000
    const int Eh = E / 2;                // 1600000 undirected pairs

    float* out_pooled   = (float*)d_out;
    float* out_seg      = out_pooled + (size_t)N * C;
    float* out_scaling  = out_seg + N;
    float* out_cb       = out_scaling + N;
    float* out_ispeak   = out_cb + N;
    float* out_istrough = out_ispeak + N;

    char* p = (char*)d_ws;
    auto alloc = [&](size_t bytes) -> char* {
        char* r = p;
        p += (bytes + 255) & ~(size_t)255;
        return r;
    };
    double* elev64 = (double*)alloc((size_t)N * 8);
    float* elev32  = (float*)alloc((size_t)N * 4);
    int* best      = (int*)alloc((size_t)N * 4);
    int* peakflag  = (int*)alloc((size_t)N * 4);
    int* new_id    = (int*)alloc((size_t)N * 4);
    int* seg       = (int*)alloc((size_t)N * 4);
    float* wbuf    = (float*)alloc((size_t)N * 4);
    const int P = (N + 255) / 256;
    int* part = (int*)alloc((size_t)P * 4);
    int* offs = (int*)alloc((size_t)P * 4);
    char* zbeg = p;  // zero-initialized region starts here
    unsigned char* notpeak   = (unsigned char*)alloc((size_t)N);
    unsigned char* nottrough = (unsigned char*)alloc((size_t)N);
    float* z   = (float*)alloc((size_t)N * 4);
    int* dcnt  = (int*)alloc(2048 * 4);
    size_t zspan = (size_t)(p - zbeg);
    int2* down0 = (int2*)alloc((size_t)E * 8);
    int2* down1 = (int2*)alloc((size_t)E * 8);
    (void)ws_size;

    hipMemsetAsync(zbeg, 0, zspan, stream);
    hipMemsetAsync(out_pooled, 0, (size_t)N * C * sizeof(float), stream);

    k_matvec<<<(N + 3) / 4, 256, 0, stream>>>(x, W, b, elev64, elev32, N, C);
    k_edgeA<<<(Eh + 255) / 256, 256, 0, stream>>>(ei, elev64, notpeak, nottrough,
                                                  down0, dcnt, Eh, E);
    k_nodes1<<<P, 256, 0, stream>>>(notpeak, nottrough, peakflag, best,
                                    out_ispeak, out_istrough, out_cb, part, N);
    // new_id = inclusive_scan(peakflag) - 1  (partials already in part)
    k_scan_offs<<<1, 64, 0, stream>>>(part, offs, P);
    k_scan_final<<<P, 256, 0, stream>>>(peakflag, offs, new_id, N);

    // edge-centric BFS over shrinking list, kernel-boundary-synchronized
    for (int L = 1; L <= NLEVELS; ++L)
        k_level_e<<<1024, 256, 0, stream>>>(down0, down1, dcnt, best, L);
    k_tail_e<<<1, 1024, 0, stream>>>(down0, down1, dcnt, best);

    k_segw<<<(N + 255) / 256, 256, 0, stream>>>(best, new_id, elev32, batch, seg,
                                                out_seg, out_cb, wbuf, z, N);
    k_pool<<<(N + 3) / 4, 256, 0, stream>>>(x, seg, wbuf, z, out_scaling,
                                            out_pooled, N, C);
}

// Round 9
// 310.041 us; speedup vs baseline: 3.2709x; 1.1604x over previous
//
#include <hip/hip_runtime.h>

#define SENT32 0x7FFFFFFF
#define IDMASK 0x1FFFF
#define RSHIFT 17
#define NLEVELS 8

// ---- 1. elevation: elev = x @ W + b, f64 accumulation, wave-per-row ----
__global__ __launch_bounds__(256) void k_matvec(const float* __restrict__ x,
                                                const float* __restrict__ W,
                                                const float* __restrict__ b,
                                                double* __restrict__ elev64,
                                                float* __restrict__ elev32,
                                                int N, int C) {
    int lane = threadIdx.x & 63;
    int wib  = threadIdx.x >> 6;
    int row  = blockIdx.x * (blockDim.x >> 6) + wib;
    if (row >= N) return;
    const float* xr = x + (size_t)row * C;
    double s = 0.0;
    for (int c = lane; c < C; c += 64) s += (double)xr[c] * (double)W[c];
#pragma unroll
    for (int off = 32; off > 0; off >>= 1) s += __shfl_down(s, off, 64);
    if (lane == 0) {
        double v = s + (double)b[0];
        elev64[row] = v;
        elev32[row] = (float)v;
    }
}

// ---- 2. mark pass over UNDIRECTED pairs (input is [src||dst ; dst||src]):
// peak/trough violation marks + per-pair 2-bit down-direction code. ----
__global__ __launch_bounds__(256) void k_mark(const int* __restrict__ ei,
                                              const double* __restrict__ elev64,
                                              unsigned char* __restrict__ notpeak,
                                              unsigned char* __restrict__ nottrough,
                                              unsigned char* __restrict__ code,
                                              int Eh, int E) {
    int e = blockIdx.x * 256 + threadIdx.x;
    if (e >= Eh) return;
    int s = ei[e];
    int d = ei[(size_t)E + e];
    double es = elev64[s], ed = elev64[d];
    if (ed < es)      { notpeak[d] = 1; nottrough[s] = 1; }
    else if (ed > es) { notpeak[s] = 1; nottrough[d] = 1; }
    code[e] = (unsigned char)((ed <= es ? 1 : 0) | (es <= ed ? 2 : 0));
}

// ---- 3. node pass: flags, best init, per-block peak partials ----
__global__ __launch_bounds__(256) void k_nodes1(const unsigned char* __restrict__ notpeak,
                                                const unsigned char* __restrict__ nottrough,
                                                int* __restrict__ peakflag,
                                                int* __restrict__ best,
                                                float* __restrict__ out_ispeak,
                                                float* __restrict__ out_istrough,
                                                float* __restrict__ out_cb,
                                                int* __restrict__ part, int N) {
    __shared__ int ws[4];
    int n = blockIdx.x * 256 + threadIdx.x;
    int lane = threadIdx.x & 63, wid = threadIdx.x >> 6;
    int pk = 0;
    if (n < N) {
        pk = notpeak[n] ? 0 : 1;
        int tr = nottrough[n] ? 0 : 1;
        peakflag[n] = pk;
        out_ispeak[n] = (float)pk;
        out_istrough[n] = (float)tr;
        best[n] = pk ? n : SENT32;
        out_cb[n] = -1.0f;
    }
    unsigned long long mk = __ballot(pk);
    if (lane == 0) ws[wid] = __popcll(mk);
    __syncthreads();
    if (threadIdx.x == 0) part[blockIdx.x] = ws[0] + ws[1] + ws[2] + ws[3];
}

// ---- 4. prefix sums (for new_id only) ----
__global__ __launch_bounds__(64) void k_scan_offs(const int* __restrict__ part,
                                                  int* __restrict__ offs, int P) {
    int lane = threadIdx.x;
    int chunk = (P + 63) / 64;
    int s0 = lane * chunk, s1 = min(s0 + chunk, P);
    int s = 0;
    for (int j = s0; j < s1; ++j) s += part[j];
    int incl = s;
#pragma unroll
    for (int off = 1; off < 64; off <<= 1) {
        int t = __shfl_up(incl, off, 64);
        if (lane >= off) incl += t;
    }
    int run = incl - s;
    for (int j = s0; j < s1; ++j) { offs[j] = run; run += part[j]; }
}

__global__ __launch_bounds__(256) void k_scan_final(const int* __restrict__ flag,
                                                    const int* __restrict__ offs,
                                                    int* __restrict__ out0, int N) {
    __shared__ int tmp[256];
    int n = blockIdx.x * 256 + threadIdx.x;
    int f = (n < N) ? flag[n] : 0;
    tmp[threadIdx.x] = f;
    __syncthreads();
    for (int off = 1; off < 256; off <<= 1) {
        int t = (threadIdx.x >= off) ? tmp[threadIdx.x - off] : 0;
        __syncthreads();
        tmp[threadIdx.x] += t;
        __syncthreads();
    }
    if (n < N) out0[n] = offs[blockIdx.x] + tmp[threadIdx.x] - 1;  // new_id
}

// ---- 5a. fused down-list build + BFS level 1 ----
// Level-1 relaxations come only from peak sources: cand = (1<<17)|src, no
// best[] gather (peak flags are stable -> race-free). Keep an edge for
// levels >= 2 iff BOTH endpoints are non-peak (dst peak: never improvable;
// src peak: consumed here). Kept edges appended contiguously (block-agg).
__global__ __launch_bounds__(256) void k_build_l1(const int* __restrict__ ei,
                                                  const unsigned char* __restrict__ code,
                                                  const unsigned char* __restrict__ notpeak,
                                                  int* __restrict__ best,
                                                  int2* __restrict__ dst,
                                                  int* __restrict__ dcnt,
                                                  int Eh, int E) {
    __shared__ int wcnt[8];
    __shared__ int wbase[8];
    int e = blockIdx.x * 256 + threadIdx.x;
    int lane = threadIdx.x & 63, wid = threadIdx.x >> 6;
    int s = 0, d = 0;
    bool k_sd = false, k_ds = false;
    if (e < Eh) {
        s = ei[e];
        d = ei[(size_t)E + e];
        int cd = code[e];
        bool ps = !notpeak[s], pd = !notpeak[d];
        if (cd & 1) {                       // down edge s->d
            if (ps) { if (!pd) atomicMin(&best[d], (1 << RSHIFT) | s); }
            else if (!pd) k_sd = true;
        }
        if (cd & 2) {                       // down edge d->s
            if (pd) { if (!ps) atomicMin(&best[s], (1 << RSHIFT) | d); }
            else if (!ps) k_ds = true;
        }
    }
    unsigned long long m1 = __ballot(k_sd);
    unsigned long long m2 = __ballot(k_ds);
    if (lane == 0) {
        wcnt[wid * 2]     = __popcll(m1);
        wcnt[wid * 2 + 1] = __popcll(m2);
    }
    __syncthreads();
    if (threadIdx.x == 0) {
        int t = 0;
#pragma unroll
        for (int i = 0; i < 8; ++i) t += wcnt[i];
        int bse = t ? atomicAdd(&dcnt[1], t) : 0;
#pragma unroll
        for (int i = 0; i < 8; ++i) { wbase[i] = bse; bse += wcnt[i]; }
    }
    __syncthreads();
    if (k_sd) dst[wbase[wid * 2] + __popcll(m1 & ((1ull << lane) - 1))] = make_int2(s, d);
    if (k_ds) dst[wbase[wid * 2 + 1] + __popcll(m2 & ((1ull << lane) - 1))] = make_int2(d, s);
}

// ---- 5b. one BFS level (L>=2): edge-centric over shrinking compacted list ----
// best[v] packs (round<<17)|label, monotone decreasing => stale reads are
// always >= actual, every race case safe. Per edge at level L:
//   round(best[src])==L-1 -> relax (atomicMin) and drop
//   else dst assigned      -> drop (future cand round > dst round, useless)
//   else                   -> keep (block-aggregated contiguous append)
__global__ __launch_bounds__(256) void k_level_e(int2* __restrict__ d0,
                                                 int2* __restrict__ d1,
                                                 int* __restrict__ dcnt,
                                                 int* __restrict__ best, int L) {
    int ne = dcnt[L - 1];
    if (ne == 0) return;
    const int2* src = ((L - 1) & 1) ? d1 : d0;
    int2* dst = (L & 1) ? d1 : d0;
    __shared__ int wcnt[4];
    __shared__ int wbase[4];
    int lane = threadIdx.x & 63, wid = threadIdx.x >> 6;
    int stride = gridDim.x * 256;
    for (int base = blockIdx.x * 256; base < ne; base += stride) {
        int i = base + threadIdx.x;
        int2 ed = make_int2(0, 0);
        bool keep = false;
        if (i < ne) {
            ed = src[i];
            int bs = best[ed.x];
            if ((bs >> RSHIFT) == L - 1) {
                int cand = bs + (1 << RSHIFT);
                if (best[ed.y] > cand) atomicMin(&best[ed.y], cand);
            } else {
                keep = (best[ed.y] == SENT32);
            }
        }
        unsigned long long mk = __ballot(keep);
        if (lane == 0) wcnt[wid] = __popcll(mk);
        __syncthreads();
        if (threadIdx.x == 0) {
            int t = wcnt[0] + wcnt[1] + wcnt[2] + wcnt[3];
            int bse = t ? atomicAdd(&dcnt[L], t) : 0;
            wbase[0] = bse;
            wbase[1] = bse + wcnt[0];
            wbase[2] = wbase[1] + wcnt[1];
            wbase[3] = wbase[2] + wcnt[2];
        }
        __syncthreads();
        if (keep) dst[wbase[wid] + __popcll(mk & ((1ull << lane) - 1))] = ed;
        __syncthreads();  // wcnt/wbase reused next iteration
    }
}

// ---- 5c. safety net: levels beyond NLEVELS, single block ----
__global__ __launch_bounds__(1024) void k_tail_e(int2* __restrict__ d0,
                                                 int2* __restrict__ d1,
                                                 int* __restrict__ dcnt,
                                                 int* __restrict__ best) {
    for (int L = NLEVELS + 1; L < 2000; ++L) {
        int ne = dcnt[L - 1];
        if (ne == 0) return;
        const int2* src = ((L - 1) & 1) ? d1 : d0;
        int2* dst = (L & 1) ? d1 : d0;
        for (int i = threadIdx.x; i < ne; i += blockDim.x) {
            int2 ed = src[i];
            int bs = best[ed.x];
            if ((bs >> RSHIFT) == L - 1) {
                int cand = bs + (1 << RSHIFT);
                if (best[ed.y] > cand) atomicMin(&best[ed.y], cand);
            } else if (best[ed.y] == SENT32) {
                int pos = atomicAdd(&dcnt[L], 1);
                dst[pos] = ed;
            }
        }
        __threadfence();
        __syncthreads();
    }
}

// ---- 6. fused: seg labels + cluster_batch + softmax weight + z.
// segmax[cluster] == elev32[peak] (watershed paths are non-increasing). ----
__global__ __launch_bounds__(256) void k_segw(const int* __restrict__ best,
                                              const int* __restrict__ new_id,
                                              const float* __restrict__ elev32,
                                              const int* __restrict__ batch,
                                              int* __restrict__ seg,
                                              float* __restrict__ out_seg,
                                              float* __restrict__ out_cb,
                                              float* __restrict__ wbuf,
                                              float* __restrict__ z, int N) {
    int n = blockIdx.x * blockDim.x + threadIdx.x;
    if (n >= N) return;
    int a = best[n];
    int sg = 0;
    float wv = 0.0f;
    if (a != SENT32) {
        int pk = a & IDMASK;              // originating peak node id
        sg = new_id[pk];
        if ((a >> RSHIFT) == 0) out_cb[sg] = (float)batch[n];  // peak node
        wv = expf(elev32[n] - elev32[pk]);
        atomicAdd(&z[sg], wv);
    }
    seg[n] = sg;
    out_seg[n] = (float)sg;
    wbuf[n] = wv;
}

// ---- 7. scaling + weighted pooling (wave-per-node, L2-side atomics) ----
__global__ __launch_bounds__(256) void k_pool(const float* __restrict__ x,
                                              const int* __restrict__ seg,
                                              const float* __restrict__ wbuf,
                                              const float* __restrict__ z,
                                              float* __restrict__ out_scaling,
                                              float* __restrict__ out_pooled,
                                              int N, int C) {
    int lane = threadIdx.x & 63;
    int node = blockIdx.x * (blockDim.x >> 6) + (threadIdx.x >> 6);
    if (node >= N) return;
    int sg = seg[node];
    float sc = wbuf[node] / (z[sg] + 1e-12f);
    if (lane == 0) out_scaling[node] = sc;
    const float* xr = x + (size_t)node * C;
    float* pr = out_pooled + (size_t)sg * C;
    for (int c = lane; c < C; c += 64) atomicAdd(&pr[c], xr[c] * sc);
}

extern "C" void kernel_launch(void* const* d_in, const int* in_sizes, int n_in,
                              void* d_out, int out_size, void* d_ws, size_t ws_size,
                              hipStream_t stream) {
    const float* x = (const float*)d_in[0];
    const float* W = (const float*)d_in[1];
    const float* b = (const float*)d_in[2];
    const int* ei = (const int*)d_in[3];
    const int* batch = (const int*)d_in[4];

    const int C = in_sizes[1];           // 128
    const int N = in_sizes[0] / C;       // 100000
    const int E = in_sizes[3] / 2;       // 3200000
    const int Eh = E / 2;                // 1600000 undirected pairs

    float* out_pooled   = (float*)d_out;
    float* out_seg      = out_pooled + (size_t)N * C;
    float* out_scaling  = out_seg + N;
    float* out_cb       = out_scaling + N;
    float* out_ispeak   = out_cb + N;
    float* out_istrough = out_ispeak + N;

    char* p = (char*)d_ws;
    auto alloc = [&](size_t bytes) -> char* {
        char* r = p;
        p += (bytes + 255) & ~(size_t)255;
        return r;
    };
    double* elev64 = (double*)alloc((size_t)N * 8);
    float* elev32  = (float*)alloc((size_t)N * 4);
    int* best      = (int*)alloc((size_t)N * 4);
    int* peakflag  = (int*)alloc((size_t)N * 4);
    int* new_id    = (int*)alloc((size_t)N * 4);
    int* seg       = (int*)alloc((size_t)N * 4);
    float* wbuf    = (float*)alloc((size_t)N * 4);
    const int P = (N + 255) / 256;
    int* part = (int*)alloc((size_t)P * 4);
    int* offs = (int*)alloc((size_t)P * 4);
    unsigned char* code = (unsigned char*)alloc((size_t)Eh);
    char* zbeg = p;  // zero-initialized region starts here
    unsigned char* notpeak   = (unsigned char*)alloc((size_t)N);
    unsigned char* nottrough = (unsigned char*)alloc((size_t)N);
    float* z   = (float*)alloc((size_t)N * 4);
    int* dcnt  = (int*)alloc(2048 * 4);
    size_t zspan = (size_t)(p - zbeg);
    int2* down0 = (int2*)alloc((size_t)E * 8);
    int2* down1 = (int2*)alloc((size_t)E * 8);
    (void)ws_size;

    hipMemsetAsync(zbeg, 0, zspan, stream);
    hipMemsetAsync(out_pooled, 0, (size_t)N * C * sizeof(float), stream);

    k_matvec<<<(N + 3) / 4, 256, 0, stream>>>(x, W, b, elev64, elev32, N, C);
    k_mark<<<(Eh + 255) / 256, 256, 0, stream>>>(ei, elev64, notpeak, nottrough,
                                                 code, Eh, E);
    k_nodes1<<<P, 256, 0, stream>>>(notpeak, nottrough, peakflag, best,
                                    out_ispeak, out_istrough, out_cb, part, N);
    // new_id = inclusive_scan(peakflag) - 1  (partials already in part)
    k_scan_offs<<<1, 64, 0, stream>>>(part, offs, P);
    k_scan_final<<<P, 256, 0, stream>>>(peakflag, offs, new_id, N);

    // fused build + level 1: kept list lands in down1 with count dcnt[1]
    k_build_l1<<<(Eh + 255) / 256, 256, 0, stream>>>(ei, code, notpeak, best,
                                                     down1, dcnt, Eh, E);
    // levels 2..NLEVELS over shrinking list, kernel-boundary-synchronized
    for (int L = 2; L <= NLEVELS; ++L)
        k_level_e<<<1024, 256, 0, stream>>>(down0, down1, dcnt, best, L);
    k_tail_e<<<1, 1024, 0, stream>>>(down0, down1, dcnt, best);

    k_segw<<<(N + 255) / 256, 256, 0, stream>>>(best, new_id, elev32, batch, seg,
                                                out_seg, out_cb, wbuf, z, N);
    k_pool<<<(N + 3) / 4, 256, 0, stream>>>(x, seg, wbuf, z, out_scaling,
                                            out_pooled, N, C);
}

// Round 10
// 289.723 us; speedup vs baseline: 3.5003x; 1.0701x over previous
//
#include <hip/hip_runtime.h>

#define SENT32 0x7FFFFFFF
#define IDMASK 0x1FFFF
#define RSHIFT 17
#define NLEVELS 8

// block-wide allocation: per-thread cnt -> contiguous base in *gctr.
// lds must be int[8]. Two __syncthreads inside; caller must barrier before
// reusing lds in a loop.
__device__ __forceinline__ int block_alloc(int cnt, int* gctr, int* lds) {
    int lane = threadIdx.x & 63, wid = threadIdx.x >> 6;
    int pfx = cnt;
#pragma unroll
    for (int off = 1; off < 64; off <<= 1) {
        int t = __shfl_up(pfx, off, 64);
        if (lane >= off) pfx += t;
    }
    if (lane == 63) lds[wid] = pfx;
    __syncthreads();
    if (threadIdx.x == 0) {
        int t = lds[0] + lds[1] + lds[2] + lds[3];
        int bse = t ? atomicAdd(gctr, t) : 0;
        lds[4] = bse;
        lds[5] = bse + lds[0];
        lds[6] = lds[5] + lds[1];
        lds[7] = lds[6] + lds[2];
    }
    __syncthreads();
    return lds[4 + wid] + pfx - cnt;
}

// ---- 1. elevation: elev = x @ W + b, f64 accumulation, wave-per-row ----
__global__ __launch_bounds__(256) void k_matvec(const float* __restrict__ x,
                                                const float* __restrict__ W,
                                                const float* __restrict__ b,
                                                double* __restrict__ elev64,
                                                float* __restrict__ elev32,
                                                int N, int C) {
    int lane = threadIdx.x & 63;
    int wib  = threadIdx.x >> 6;
    int row  = blockIdx.x * (blockDim.x >> 6) + wib;
    if (row >= N) return;
    const float* xr = x + (size_t)row * C;
    double s = 0.0;
    for (int c = lane; c < C; c += 64) s += (double)xr[c] * (double)W[c];
#pragma unroll
    for (int off = 32; off > 0; off >>= 1) s += __shfl_down(s, off, 64);
    if (lane == 0) {
        double v = s + (double)b[0];
        elev64[row] = v;
        elev32[row] = (float)v;
    }
}

// ---- 2. mark pass, 4 undirected pairs per thread (input [src||dst;dst||src]):
// peak/trough violation marks + per-pair 2-bit down-direction code. ----
__global__ __launch_bounds__(256) void k_mark(const int* __restrict__ ei,
                                              const double* __restrict__ elev64,
                                              unsigned char* __restrict__ notpeak,
                                              unsigned char* __restrict__ nottrough,
                                              unsigned char* __restrict__ code,
                                              int Eh, int E) {
    int t0 = (blockIdx.x * 256 + threadIdx.x) * 4;
    if (t0 >= Eh) return;
    int s[4], d[4];
    int nv = 4;
    if (t0 + 4 <= Eh) {
        int4 sv = *(const int4*)&ei[t0];
        int4 dv = *(const int4*)&ei[(size_t)E + t0];
        s[0] = sv.x; s[1] = sv.y; s[2] = sv.z; s[3] = sv.w;
        d[0] = dv.x; d[1] = dv.y; d[2] = dv.z; d[3] = dv.w;
    } else {
        nv = Eh - t0;
        for (int j = 0; j < nv; ++j) { s[j] = ei[t0 + j]; d[j] = ei[(size_t)E + t0 + j]; }
        for (int j = nv; j < 4; ++j) { s[j] = 0; d[j] = 0; }
    }
    double es[4], ed[4];
#pragma unroll
    for (int j = 0; j < 4; ++j) { es[j] = elev64[s[j]]; ed[j] = elev64[d[j]]; }
    unsigned cw = 0;
#pragma unroll
    for (int j = 0; j < 4; ++j) {
        if (j < nv) {
            if (ed[j] < es[j])      { notpeak[d[j]] = 1; nottrough[s[j]] = 1; }
            else if (ed[j] > es[j]) { notpeak[s[j]] = 1; nottrough[d[j]] = 1; }
            unsigned c = (ed[j] <= es[j] ? 1u : 0u) | (es[j] <= ed[j] ? 2u : 0u);
            cw |= c << (8 * j);
        }
    }
    if (nv == 4) *(unsigned*)&code[t0] = cw;
    else for (int j = 0; j < nv; ++j) code[t0 + j] = (unsigned char)((cw >> (8 * j)) & 0xFF);
}

// ---- 3. node pass: flags, best init, per-block peak partials ----
__global__ __launch_bounds__(256) void k_nodes1(const unsigned char* __restrict__ notpeak,
                                                const unsigned char* __restrict__ nottrough,
                                                int* __restrict__ peakflag,
                                                int* __restrict__ best,
                                                float* __restrict__ out_ispeak,
                                                float* __restrict__ out_istrough,
                                                float* __restrict__ out_cb,
                                                int* __restrict__ part, int N) {
    __shared__ int ws[4];
    int n = blockIdx.x * 256 + threadIdx.x;
    int lane = threadIdx.x & 63, wid = threadIdx.x >> 6;
    int pk = 0;
    if (n < N) {
        pk = notpeak[n] ? 0 : 1;
        int tr = nottrough[n] ? 0 : 1;
        peakflag[n] = pk;
        out_ispeak[n] = (float)pk;
        out_istrough[n] = (float)tr;
        best[n] = pk ? n : SENT32;
        out_cb[n] = -1.0f;
    }
    unsigned long long mk = __ballot(pk);
    if (lane == 0) ws[wid] = __popcll(mk);
    __syncthreads();
    if (threadIdx.x == 0) part[blockIdx.x] = ws[0] + ws[1] + ws[2] + ws[3];
}

// ---- 4. prefix sums (for new_id only) ----
__global__ __launch_bounds__(64) void k_scan_offs(const int* __restrict__ part,
                                                  int* __restrict__ offs, int P) {
    int lane = threadIdx.x;
    int chunk = (P + 63) / 64;
    int s0 = lane * chunk, s1 = min(s0 + chunk, P);
    int s = 0;
    for (int j = s0; j < s1; ++j) s += part[j];
    int incl = s;
#pragma unroll
    for (int off = 1; off < 64; off <<= 1) {
        int t = __shfl_up(incl, off, 64);
        if (lane >= off) incl += t;
    }
    int run = incl - s;
    for (int j = s0; j < s1; ++j) { offs[j] = run; run += part[j]; }
}

__global__ __launch_bounds__(256) void k_scan_final(const int* __restrict__ flag,
                                                    const int* __restrict__ offs,
                                                    int* __restrict__ out0, int N) {
    __shared__ int tmp[256];
    int n = blockIdx.x * 256 + threadIdx.x;
    int f = (n < N) ? flag[n] : 0;
    tmp[threadIdx.x] = f;
    __syncthreads();
    for (int off = 1; off < 256; off <<= 1) {
        int t = (threadIdx.x >= off) ? tmp[threadIdx.x - off] : 0;
        __syncthreads();
        tmp[threadIdx.x] += t;
        __syncthreads();
    }
    if (n < N) out0[n] = offs[blockIdx.x] + tmp[threadIdx.x] - 1;  // new_id
}

// ---- 5a. fused down-list build + BFS level 1, 4 pairs per thread ----
// Level-1 relaxations come only from peak sources: cand = (1<<17)|src, no
// best[] gather (peak flags are stable -> race-free). Keep an edge for
// levels >= 2 iff BOTH endpoints are non-peak. Kept edges appended
// contiguously via block_alloc.
__global__ __launch_bounds__(256) void k_build_l1(const int* __restrict__ ei,
                                                  const unsigned char* __restrict__ code,
                                                  const unsigned char* __restrict__ notpeak,
                                                  int* __restrict__ best,
                                                  int2* __restrict__ dst,
                                                  int* __restrict__ dcnt,
                                                  int Eh, int E) {
    __shared__ int lds[8];
    int t0 = (blockIdx.x * 256 + threadIdx.x) * 4;
    int s[4], d[4];
    unsigned cw = 0;
    int nv = 0;
    if (t0 + 4 <= Eh) {
        nv = 4;
        int4 sv = *(const int4*)&ei[t0];
        int4 dv = *(const int4*)&ei[(size_t)E + t0];
        s[0] = sv.x; s[1] = sv.y; s[2] = sv.z; s[3] = sv.w;
        d[0] = dv.x; d[1] = dv.y; d[2] = dv.z; d[3] = dv.w;
        cw = *(const unsigned*)&code[t0];
    } else if (t0 < Eh) {
        nv = Eh - t0;
        for (int j = 0; j < nv; ++j) {
            s[j] = ei[t0 + j]; d[j] = ei[(size_t)E + t0 + j];
            cw |= (unsigned)code[t0 + j] << (8 * j);
        }
        for (int j = nv; j < 4; ++j) { s[j] = 0; d[j] = 0; }
    } else {
        s[0] = s[1] = s[2] = s[3] = 0;
        d[0] = d[1] = d[2] = d[3] = 0;
    }
    unsigned char nps[4], npd[4];
#pragma unroll
    for (int j = 0; j < 4; ++j) { nps[j] = notpeak[s[j]]; npd[j] = notpeak[d[j]]; }
    bool k1[4], k2[4];
    int cnt = 0;
#pragma unroll
    for (int j = 0; j < 4; ++j) {
        k1[j] = k2[j] = false;
        if (j < nv) {
            unsigned cd = (cw >> (8 * j)) & 0xFF;
            bool ps = !nps[j], pd = !npd[j];
            if (cd & 1) {                     // down edge s->d
                if (ps) { if (!pd) atomicMin(&best[d[j]], (1 << RSHIFT) | s[j]); }
                else if (!pd) { k1[j] = true; ++cnt; }
            }
            if (cd & 2) {                     // down edge d->s
                if (pd) { if (!ps) atomicMin(&best[s[j]], (1 << RSHIFT) | d[j]); }
                else if (!ps) { k2[j] = true; ++cnt; }
            }
        }
    }
    int base = block_alloc(cnt, &dcnt[1], lds);
#pragma unroll
    for (int j = 0; j < 4; ++j) {
        if (k1[j]) dst[base++] = make_int2(s[j], d[j]);
        if (k2[j]) dst[base++] = make_int2(d[j], s[j]);
    }
}

// ---- 5b. one BFS level (L>=2): 4 edges/thread over shrinking list ----
// best[v] packs (round<<17)|label, monotone decreasing => stale reads are
// always >= actual, every race case safe. Per edge at level L:
//   round(best[src])==L-1 -> relax (atomicMin) and drop
//   else dst assigned      -> drop
//   else                   -> keep (block_alloc contiguous append)
__global__ __launch_bounds__(256) void k_level_e(int2* __restrict__ d0,
                                                 int2* __restrict__ d1,
                                                 int* __restrict__ dcnt,
                                                 int* __restrict__ best, int L) {
    int ne = dcnt[L - 1];
    if (ne == 0) return;
    const int2* src = ((L - 1) & 1) ? d1 : d0;
    int2* dst = (L & 1) ? d1 : d0;
    __shared__ int lds[8];
    int stride = gridDim.x * 1024;
    for (int base = blockIdx.x * 1024; base < ne; base += stride) {
        int i0 = base + threadIdx.x * 4;
        int2 e[4];
        int nv = 0;
        if (i0 + 4 <= ne) {
            nv = 4;
            int4 a = *(const int4*)&src[i0];
            int4 b2 = *(const int4*)&src[i0 + 2];
            e[0] = make_int2(a.x, a.y);  e[1] = make_int2(a.z, a.w);
            e[2] = make_int2(b2.x, b2.y); e[3] = make_int2(b2.z, b2.w);
        } else if (i0 < ne) {
            nv = ne - i0;
            for (int j = 0; j < nv; ++j) e[j] = src[i0 + j];
            for (int j = nv; j < 4; ++j) e[j] = make_int2(0, 0);
        } else {
            e[0] = e[1] = e[2] = e[3] = make_int2(0, 0);
        }
        int bs[4], by[4];
#pragma unroll
        for (int j = 0; j < 4; ++j) { bs[j] = best[e[j].x]; by[j] = best[e[j].y]; }
        bool keep[4];
        int cnt = 0;
#pragma unroll
        for (int j = 0; j < 4; ++j) {
            keep[j] = false;
            if (j < nv) {
                if ((bs[j] >> RSHIFT) == L - 1) {
                    int cand = bs[j] + (1 << RSHIFT);
                    if (by[j] > cand) atomicMin(&best[e[j].y], cand);
                } else if (by[j] == SENT32) {
                    keep[j] = true; ++cnt;
                }
            }
        }
        int wbase = block_alloc(cnt, &dcnt[L], lds);
#pragma unroll
        for (int j = 0; j < 4; ++j)
            if (keep[j]) dst[wbase++] = e[j];
        __syncthreads();  // lds reused next iteration
    }
}

// ---- 5c. safety net: levels beyond NLEVELS, single block ----
__global__ __launch_bounds__(1024) void k_tail_e(int2* __restrict__ d0,
                                                 int2* __restrict__ d1,
                                                 int* __restrict__ dcnt,
                                                 int* __restrict__ best) {
    for (int L = NLEVELS + 1; L < 2000; ++L) {
        int ne = dcnt[L - 1];
        if (ne == 0) return;
        const int2* src = ((L - 1) & 1) ? d1 : d0;
        int2* dst = (L & 1) ? d1 : d0;
        for (int i = threadIdx.x; i < ne; i += blockDim.x) {
            int2 ed = src[i];
            int bs = best[ed.x];
            if ((bs >> RSHIFT) == L - 1) {
                int cand = bs + (1 << RSHIFT);
                if (best[ed.y] > cand) atomicMin(&best[ed.y], cand);
            } else if (best[ed.y] == SENT32) {
                int pos = atomicAdd(&dcnt[L], 1);
                dst[pos] = ed;
            }
        }
        __threadfence();
        __syncthreads();
    }
}

// ---- 6. fused: seg labels + cluster_batch + softmax weight + z.
// segmax[cluster] == elev32[peak] (watershed paths are non-increasing). ----
__global__ __launch_bounds__(256) void k_segw(const int* __restrict__ best,
                                              const int* __restrict__ new_id,
                                              const float* __restrict__ elev32,
                                              const int* __restrict__ batch,
                                              int* __restrict__ seg,
                                              float* __restrict__ out_seg,
                                              float* __restrict__ out_cb,
                                              float* __restrict__ wbuf,
                                              float* __restrict__ z, int N) {
    int n = blockIdx.x * blockDim.x + threadIdx.x;
    if (n >= N) return;
    int a = best[n];
    int sg = 0;
    float wv = 0.0f;
    if (a != SENT32) {
        int pk = a & IDMASK;              // originating peak node id
        sg = new_id[pk];
        if ((a >> RSHIFT) == 0) out_cb[sg] = (float)batch[n];  // peak node
        wv = expf(elev32[n] - elev32[pk]);
        atomicAdd(&z[sg], wv);
    }
    seg[n] = sg;
    out_seg[n] = (float)sg;
    wbuf[n] = wv;
}

// ---- 7. scaling + weighted pooling (wave-per-node, L2-side atomics) ----
__global__ __launch_bounds__(256) void k_pool(const float* __restrict__ x,
                                              const int* __restrict__ seg,
                                              const float* __restrict__ wbuf,
                                              const float* __restrict__ z,
                                              float* __restrict__ out_scaling,
                                              float* __restrict__ out_pooled,
                                              int N, int C) {
    int lane = threadIdx.x & 63;
    int node = blockIdx.x * (blockDim.x >> 6) + (threadIdx.x >> 6);
    if (node >= N) return;
    int sg = seg[node];
    float sc = wbuf[node] / (z[sg] + 1e-12f);
    if (lane == 0) out_scaling[node] = sc;
    const float* xr = x + (size_t)node * C;
    float* pr = out_pooled + (size_t)sg * C;
    for (int c = lane; c < C; c += 64) atomicAdd(&pr[c], xr[c] * sc);
}

extern "C" void kernel_launch(void* const* d_in, const int* in_sizes, int n_in,
                              void* d_out, int out_size, void* d_ws, size_t ws_size,
                              hipStream_t stream) {
    const float* x = (const float*)d_in[0];
    const float* W = (const float*)d_in[1];
    const float* b = (const float*)d_in[2];
    const int* ei = (const int*)d_in[3];
    const int* batch = (const int*)d_in[4];

    const int C = in_sizes[1];           // 128
    const int N = in_sizes[0] / C;       // 100000
    const int E = in_sizes[3] / 2;       // 3200000
    const int Eh = E / 2;                // 1600000 undirected pairs

    float* out_pooled   = (float*)d_out;
    float* out_seg      = out_pooled + (size_t)N * C;
    float* out_scaling  = out_seg + N;
    float* out_cb       = out_scaling + N;
    float* out_ispeak   = out_cb + N;
    float* out_istrough = out_ispeak + N;

    char* p = (char*)d_ws;
    auto alloc = [&](size_t bytes) -> char* {
        char* r = p;
        p += (bytes + 255) & ~(size_t)255;
        return r;
    };
    double* elev64 = (double*)alloc((size_t)N * 8);
    float* elev32  = (float*)alloc((size_t)N * 4);
    int* best      = (int*)alloc((size_t)N * 4);
    int* peakflag  = (int*)alloc((size_t)N * 4);
    int* new_id    = (int*)alloc((size_t)N * 4);
    int* seg       = (int*)alloc((size_t)N * 4);
    float* wbuf    = (float*)alloc((size_t)N * 4);
    const int P = (N + 255) / 256;
    int* part = (int*)alloc((size_t)P * 4);
    int* offs = (int*)alloc((size_t)P * 4);
    unsigned char* code = (unsigned char*)alloc((size_t)Eh);
    char* zbeg = p;  // zero-initialized region starts here
    unsigned char* notpeak   = (unsigned char*)alloc((size_t)N);
    unsigned char* nottrough = (unsigned char*)alloc((size_t)N);
    float* z   = (float*)alloc((size_t)N * 4);
    int* dcnt  = (int*)alloc(2048 * 4);
    size_t zspan = (size_t)(p - zbeg);
    int2* down0 = (int2*)alloc((size_t)E * 8);
    int2* down1 = (int2*)alloc((size_t)E * 8);
    (void)ws_size;

    hipMemsetAsync(zbeg, 0, zspan, stream);
    hipMemsetAsync(out_pooled, 0, (size_t)N * C * sizeof(float), stream);

    const int B4 = (Eh + 1023) / 1024;   // 4 pairs per thread

    k_matvec<<<(N + 3) / 4, 256, 0, stream>>>(x, W, b, elev64, elev32, N, C);
    k_mark<<<B4, 256, 0, stream>>>(ei, elev64, notpeak, nottrough, code, Eh, E);
    k_nodes1<<<P, 256, 0, stream>>>(notpeak, nottrough, peakflag, best,
                                    out_ispeak, out_istrough, out_cb, part, N);
    // new_id = inclusive_scan(peakflag) - 1  (partials already in part)
    k_scan_offs<<<1, 64, 0, stream>>>(part, offs, P);
    k_scan_final<<<P, 256, 0, stream>>>(peakflag, offs, new_id, N);

    // fused build + level 1: kept list lands in down1 with count dcnt[1]
    k_build_l1<<<B4, 256, 0, stream>>>(ei, code, notpeak, best, down1, dcnt, Eh, E);
    // levels 2..NLEVELS over shrinking list, kernel-boundary-synchronized
    for (int L = 2; L <= NLEVELS; ++L)
        k_level_e<<<512, 256, 0, stream>>>(down0, down1, dcnt, best, L);
    k_tail_e<<<1, 1024, 0, stream>>>(down0, down1, dcnt, best);

    k_segw<<<(N + 255) / 256, 256, 0, stream>>>(best, new_id, elev32, batch, seg,
                                                out_seg, out_cb, wbuf, z, N);
    k_pool<<<(N + 3) / 4, 256, 0, stream>>>(x, seg, wbuf, z, out_scaling,
                                            out_pooled, N, C);
}

// Round 11
// 283.431 us; speedup vs baseline: 3.5780x; 1.0222x over previous
//
#include <hip/hip_runtime.h>

#define SENT32 0x7FFFFFFF
#define IDMASK 0x1FFFF
#define RSHIFT 17
#define NLEVELS 8

// block-wide allocation: per-thread cnt -> contiguous base in *gctr.
// lds must be int[8]. Two __syncthreads inside; caller must barrier before
// reusing lds in a loop.
__device__ __forceinline__ int block_alloc(int cnt, int* gctr, int* lds) {
    int lane = threadIdx.x & 63, wid = threadIdx.x >> 6;
    int pfx = cnt;
#pragma unroll
    for (int off = 1; off < 64; off <<= 1) {
        int t = __shfl_up(pfx, off, 64);
        if (lane >= off) pfx += t;
    }
    if (lane == 63) lds[wid] = pfx;
    __syncthreads();
    if (threadIdx.x == 0) {
        int t = lds[0] + lds[1] + lds[2] + lds[3];
        int bse = t ? atomicAdd(gctr, t) : 0;
        lds[4] = bse;
        lds[5] = bse + lds[0];
        lds[6] = lds[5] + lds[1];
        lds[7] = lds[6] + lds[2];
    }
    __syncthreads();
    return lds[4 + wid] + pfx - cnt;
}

// ---- 1. elevation: elev = x @ W + b, f64 accumulation, wave-per-row ----
__global__ __launch_bounds__(256) void k_matvec(const float* __restrict__ x,
                                                const float* __restrict__ W,
                                                const float* __restrict__ b,
                                                double* __restrict__ elev64,
                                                float* __restrict__ elev32,
                                                int N, int C) {
    int lane = threadIdx.x & 63;
    int wib  = threadIdx.x >> 6;
    int row  = blockIdx.x * (blockDim.x >> 6) + wib;
    if (row >= N) return;
    const float* xr = x + (size_t)row * C;
    double s = 0.0;
    for (int c = lane; c < C; c += 64) s += (double)xr[c] * (double)W[c];
#pragma unroll
    for (int off = 32; off > 0; off >>= 1) s += __shfl_down(s, off, 64);
    if (lane == 0) {
        double v = s + (double)b[0];
        elev64[row] = v;
        elev32[row] = (float)v;
    }
}

// ---- 2. mark pass, 4 undirected pairs per thread (input [src||dst;dst||src]):
// peak/trough violation marks + per-pair 2-bit down-direction code.
// All lanes explicit scalars: no dynamically-indexed private arrays. ----
__global__ __launch_bounds__(256) void k_mark(const int* __restrict__ ei,
                                              const double* __restrict__ elev64,
                                              unsigned char* __restrict__ notpeak,
                                              unsigned char* __restrict__ nottrough,
                                              unsigned char* __restrict__ code,
                                              int Eh, int E) {
    int t0 = (blockIdx.x * 256 + threadIdx.x) * 4;
    if (t0 >= Eh) return;
    bool v0 = true, v1 = (t0 + 1 < Eh), v2 = (t0 + 2 < Eh), v3 = (t0 + 3 < Eh);
    int s0 = 0, s1 = 0, s2 = 0, s3 = 0, d0 = 0, d1 = 0, d2 = 0, d3 = 0;
    if (v3) {
        int4 sv = *(const int4*)&ei[t0];
        int4 dv = *(const int4*)&ei[(size_t)E + t0];
        s0 = sv.x; s1 = sv.y; s2 = sv.z; s3 = sv.w;
        d0 = dv.x; d1 = dv.y; d2 = dv.z; d3 = dv.w;
    } else {
        s0 = ei[t0];            d0 = ei[(size_t)E + t0];
        if (v1) { s1 = ei[t0 + 1]; d1 = ei[(size_t)E + t0 + 1]; }
        if (v2) { s2 = ei[t0 + 2]; d2 = ei[(size_t)E + t0 + 2]; }
    }
    double es0 = elev64[s0], es1 = elev64[s1], es2 = elev64[s2], es3 = elev64[s3];
    double ed0 = elev64[d0], ed1 = elev64[d1], ed2 = elev64[d2], ed3 = elev64[d3];
    unsigned cw = 0;
#define MARK1(J, VV, SS, DD, ES, ED)                                          \
    if (VV) {                                                                 \
        if (ED < ES)      { notpeak[DD] = 1; nottrough[SS] = 1; }             \
        else if (ED > ES) { notpeak[SS] = 1; nottrough[DD] = 1; }             \
        cw |= ((ED <= ES ? 1u : 0u) | (ES <= ED ? 2u : 0u)) << (8 * J);       \
    }
    MARK1(0, v0, s0, d0, es0, ed0)
    MARK1(1, v1, s1, d1, es1, ed1)
    MARK1(2, v2, s2, d2, es2, ed2)
    MARK1(3, v3, s3, d3, es3, ed3)
#undef MARK1
    if (v3) {
        *(unsigned*)&code[t0] = cw;
    } else {
        code[t0] = (unsigned char)(cw & 0xFF);
        if (v1) code[t0 + 1] = (unsigned char)((cw >> 8) & 0xFF);
        if (v2) code[t0 + 2] = (unsigned char)((cw >> 16) & 0xFF);
    }
}

// ---- 3. node pass: flags, best init, per-block peak partials ----
__global__ __launch_bounds__(256) void k_nodes1(const unsigned char* __restrict__ notpeak,
                                                const unsigned char* __restrict__ nottrough,
                                                int* __restrict__ peakflag,
                                                int* __restrict__ best,
                                                float* __restrict__ out_ispeak,
                                                float* __restrict__ out_istrough,
                                                float* __restrict__ out_cb,
                                                int* __restrict__ part, int N) {
    __shared__ int ws[4];
    int n = blockIdx.x * 256 + threadIdx.x;
    int lane = threadIdx.x & 63, wid = threadIdx.x >> 6;
    int pk = 0;
    if (n < N) {
        pk = notpeak[n] ? 0 : 1;
        int tr = nottrough[n] ? 0 : 1;
        peakflag[n] = pk;
        out_ispeak[n] = (float)pk;
        out_istrough[n] = (float)tr;
        best[n] = pk ? n : SENT32;
        out_cb[n] = -1.0f;
    }
    unsigned long long mk = __ballot(pk);
    if (lane == 0) ws[wid] = __popcll(mk);
    __syncthreads();
    if (threadIdx.x == 0) part[blockIdx.x] = ws[0] + ws[1] + ws[2] + ws[3];
}

// ---- 4. prefix sums (for new_id only) ----
__global__ __launch_bounds__(64) void k_scan_offs(const int* __restrict__ part,
                                                  int* __restrict__ offs, int P) {
    int lane = threadIdx.x;
    int chunk = (P + 63) / 64;
    int s0 = lane * chunk, s1 = min(s0 + chunk, P);
    int s = 0;
    for (int j = s0; j < s1; ++j) s += part[j];
    int incl = s;
#pragma unroll
    for (int off = 1; off < 64; off <<= 1) {
        int t = __shfl_up(incl, off, 64);
        if (lane >= off) incl += t;
    }
    int run = incl - s;
    for (int j = s0; j < s1; ++j) { offs[j] = run; run += part[j]; }
}

__global__ __launch_bounds__(256) void k_scan_final(const int* __restrict__ flag,
                                                    const int* __restrict__ offs,
                                                    int* __restrict__ out0, int N) {
    __shared__ int tmp[256];
    int n = blockIdx.x * 256 + threadIdx.x;
    int f = (n < N) ? flag[n] : 0;
    tmp[threadIdx.x] = f;
    __syncthreads();
    for (int off = 1; off < 256; off <<= 1) {
        int t = (threadIdx.x >= off) ? tmp[threadIdx.x - off] : 0;
        __syncthreads();
        tmp[threadIdx.x] += t;
        __syncthreads();
    }
    if (n < N) out0[n] = offs[blockIdx.x] + tmp[threadIdx.x] - 1;  // new_id
}

// ---- 5a. fused down-list build + BFS level 1, 4 pairs per thread ----
// Level-1 relaxations come only from peak sources: cand = (1<<17)|src, no
// best[] gather (peak flags are stable -> race-free). Keep an edge for
// levels >= 2 iff BOTH endpoints are non-peak. Kept edges appended
// contiguously via block_alloc. Explicit scalar lanes (registers only).
__global__ __launch_bounds__(256) void k_build_l1(const int* __restrict__ ei,
                                                  const unsigned char* __restrict__ code,
                                                  const unsigned char* __restrict__ notpeak,
                                                  int* __restrict__ best,
                                                  int2* __restrict__ dst,
                                                  int* __restrict__ dcnt,
                                                  int Eh, int E) {
    __shared__ int lds[8];
    int t0 = (blockIdx.x * 256 + threadIdx.x) * 4;
    bool in = (t0 < Eh);
    bool v0 = in, v1 = (t0 + 1 < Eh), v2 = (t0 + 2 < Eh), v3 = (t0 + 3 < Eh);
    int s0 = 0, s1 = 0, s2 = 0, s3 = 0, d0 = 0, d1 = 0, d2 = 0, d3 = 0;
    unsigned cw = 0;
    if (v3) {
        int4 sv = *(const int4*)&ei[t0];
        int4 dv = *(const int4*)&ei[(size_t)E + t0];
        s0 = sv.x; s1 = sv.y; s2 = sv.z; s3 = sv.w;
        d0 = dv.x; d1 = dv.y; d2 = dv.z; d3 = dv.w;
        cw = *(const unsigned*)&code[t0];
    } else if (in) {
        s0 = ei[t0];            d0 = ei[(size_t)E + t0];
        cw = (unsigned)code[t0];
        if (v1) { s1 = ei[t0 + 1]; d1 = ei[(size_t)E + t0 + 1];
                  cw |= (unsigned)code[t0 + 1] << 8; }
        if (v2) { s2 = ei[t0 + 2]; d2 = ei[(size_t)E + t0 + 2];
                  cw |= (unsigned)code[t0 + 2] << 16; }
    }
    unsigned char np_s0 = notpeak[s0], np_s1 = notpeak[s1],
                  np_s2 = notpeak[s2], np_s3 = notpeak[s3];
    unsigned char np_d0 = notpeak[d0], np_d1 = notpeak[d1],
                  np_d2 = notpeak[d2], np_d3 = notpeak[d3];
    bool ka0 = false, ka1 = false, ka2 = false, ka3 = false;
    bool kb0 = false, kb1 = false, kb2 = false, kb3 = false;
    int cnt = 0;
#define BUILD1(J, VV, SS, DD, NPS, NPD, KA, KB)                               \
    if (VV) {                                                                 \
        unsigned cd = (cw >> (8 * J)) & 0xFFu;                                \
        bool ps = !NPS, pd = !NPD;                                            \
        if (cd & 1u) {                                                        \
            if (ps) { if (!pd) atomicMin(&best[DD], (1 << RSHIFT) | SS); }    \
            else if (!pd) { KA = true; ++cnt; }                               \
        }                                                                     \
        if (cd & 2u) {                                                        \
            if (pd) { if (!ps) atomicMin(&best[SS], (1 << RSHIFT) | DD); }    \
            else if (!ps) { KB = true; ++cnt; }                               \
        }                                                                     \
    }
    BUILD1(0, v0, s0, d0, np_s0, np_d0, ka0, kb0)
    BUILD1(1, v1, s1, d1, np_s1, np_d1, ka1, kb1)
    BUILD1(2, v2, s2, d2, np_s2, np_d2, ka2, kb2)
    BUILD1(3, v3, s3, d3, np_s3, np_d3, ka3, kb3)
#undef BUILD1
    int base = block_alloc(cnt, &dcnt[1], lds);
    if (ka0) dst[base++] = make_int2(s0, d0);
    if (kb0) dst[base++] = make_int2(d0, s0);
    if (ka1) dst[base++] = make_int2(s1, d1);
    if (kb1) dst[base++] = make_int2(d1, s1);
    if (ka2) dst[base++] = make_int2(s2, d2);
    if (kb2) dst[base++] = make_int2(d2, s2);
    if (ka3) dst[base++] = make_int2(s3, d3);
    if (kb3) dst[base]   = make_int2(d3, s3);
}

// ---- 5b. one BFS level (L>=2): 4 edges/thread over shrinking list ----
// best[v] packs (round<<17)|label, monotone decreasing => stale reads are
// always >= actual, every race case safe. Per edge at level L:
//   round(best[src])==L-1 -> relax (atomicMin) and drop
//   else dst assigned      -> drop
//   else                   -> keep (block_alloc contiguous append)
// Explicit scalar lanes; grid sized for full occupancy.
__global__ __launch_bounds__(256) void k_level_e(int2* __restrict__ d0p,
                                                 int2* __restrict__ d1p,
                                                 int* __restrict__ dcnt,
                                                 int* __restrict__ best, int L) {
    int ne = dcnt[L - 1];
    if (ne == 0) return;
    const int2* src = ((L - 1) & 1) ? d1p : d0p;
    int2* dst = (L & 1) ? d1p : d0p;
    __shared__ int lds[8];
    int stride = gridDim.x * 1024;
    for (int base = blockIdx.x * 1024; base < ne; base += stride) {
        int i0 = base + threadIdx.x * 4;
        int2 e0 = make_int2(0, 0), e1 = e0, e2 = e0, e3 = e0;
        bool v0 = (i0 < ne), v1 = (i0 + 1 < ne), v2 = (i0 + 2 < ne), v3 = (i0 + 3 < ne);
        if (v3) {
            int4 a = *(const int4*)&src[i0];
            int4 b2 = *(const int4*)&src[i0 + 2];
            e0 = make_int2(a.x, a.y);   e1 = make_int2(a.z, a.w);
            e2 = make_int2(b2.x, b2.y); e3 = make_int2(b2.z, b2.w);
        } else {
            if (v0) e0 = src[i0];
            if (v1) e1 = src[i0 + 1];
            if (v2) e2 = src[i0 + 2];
        }
        int bs0 = best[e0.x], bs1 = best[e1.x], bs2 = best[e2.x], bs3 = best[e3.x];
        int by0 = best[e0.y], by1 = best[e1.y], by2 = best[e2.y], by3 = best[e3.y];
        bool k0 = false, k1 = false, k2 = false, k3 = false;
        int cnt = 0;
#define LEVEL1(VV, EE, BS, BY, KK)                                            \
    if (VV) {                                                                 \
        if ((BS >> RSHIFT) == L - 1) {                                        \
            int cand = BS + (1 << RSHIFT);                                    \
            if (BY > cand) atomicMin(&best[EE.y], cand);                      \
        } else if (BY == SENT32) { KK = true; ++cnt; }                        \
    }
        LEVEL1(v0, e0, bs0, by0, k0)
        LEVEL1(v1, e1, bs1, by1, k1)
        LEVEL1(v2, e2, bs2, by2, k2)
        LEVEL1(v3, e3, bs3, by3, k3)
#undef LEVEL1
        int wbase = block_alloc(cnt, &dcnt[L], lds);
        if (k0) dst[wbase++] = e0;
        if (k1) dst[wbase++] = e1;
        if (k2) dst[wbase++] = e2;
        if (k3) dst[wbase]   = e3;
        __syncthreads();  // lds reused next iteration
    }
}

// ---- 5c. safety net: levels beyond NLEVELS, single block ----
__global__ __launch_bounds__(1024) void k_tail_e(int2* __restrict__ d0p,
                                                 int2* __restrict__ d1p,
                                                 int* __restrict__ dcnt,
                                                 int* __restrict__ best) {
    for (int L = NLEVELS + 1; L < 2000; ++L) {
        int ne = dcnt[L - 1];
        if (ne == 0) return;
        const int2* src = ((L - 1) & 1) ? d1p : d0p;
        int2* dst = (L & 1) ? d1p : d0p;
        for (int i = threadIdx.x; i < ne; i += blockDim.x) {
            int2 ed = src[i];
            int bs = best[ed.x];
            if ((bs >> RSHIFT) == L - 1) {
                int cand = bs + (1 << RSHIFT);
                if (best[ed.y] > cand) atomicMin(&best[ed.y], cand);
            } else if (best[ed.y] == SENT32) {
                int pos = atomicAdd(&dcnt[L], 1);
                dst[pos] = ed;
            }
        }
        __threadfence();
        __syncthreads();
    }
}

// ---- 6. fused: seg labels + cluster_batch + softmax weight + z.
// segmax[cluster] == elev32[peak] (watershed paths are non-increasing). ----
__global__ __launch_bounds__(256) void k_segw(const int* __restrict__ best,
                                              const int* __restrict__ new_id,
                                              const float* __restrict__ elev32,
                                              const int* __restrict__ batch,
                                              int* __restrict__ seg,
                                              float* __restrict__ out_seg,
                                              float* __restrict__ out_cb,
                                              float* __restrict__ wbuf,
                                              float* __restrict__ z, int N) {
    int n = blockIdx.x * blockDim.x + threadIdx.x;
    if (n >= N) return;
    int a = best[n];
    int sg = 0;
    float wv = 0.0f;
    if (a != SENT32) {
        int pk = a & IDMASK;              // originating peak node id
        sg = new_id[pk];
        if ((a >> RSHIFT) == 0) out_cb[sg] = (float)batch[n];  // peak node
        wv = expf(elev32[n] - elev32[pk]);
        atomicAdd(&z[sg], wv);
    }
    seg[n] = sg;
    out_seg[n] = (float)sg;
    wbuf[n] = wv;
}

// ---- 7. scaling + weighted pooling (wave-per-node, L2-side atomics) ----
__global__ __launch_bounds__(256) void k_pool(const float* __restrict__ x,
                                              const int* __restrict__ seg,
                                              const float* __restrict__ wbuf,
                                              const float* __restrict__ z,
                                              float* __restrict__ out_scaling,
                                              float* __restrict__ out_pooled,
                                              int N, int C) {
    int lane = threadIdx.x & 63;
    int node = blockIdx.x * (blockDim.x >> 6) + (threadIdx.x >> 6);
    if (node >= N) return;
    int sg = seg[node];
    float sc = wbuf[node] / (z[sg] + 1e-12f);
    if (lane == 0) out_scaling[node] = sc;
    const float* xr = x + (size_t)node * C;
    float* pr = out_pooled + (size_t)sg * C;
    for (int c = lane; c < C; c += 64) atomicAdd(&pr[c], xr[c] * sc);
}

extern "C" void kernel_launch(void* const* d_in, const int* in_sizes, int n_in,
                              void* d_out, int out_size, void* d_ws, size_t ws_size,
                              hipStream_t stream) {
    const float* x = (const float*)d_in[0];
    const float* W = (const float*)d_in[1];
    const float* b = (const float*)d_in[2];
    const int* ei = (const int*)d_in[3];
    const int* batch = (const int*)d_in[4];

    const int C = in_sizes[1];           // 128
    const int N = in_sizes[0] / C;       // 100000
    const int E = in_sizes[3] / 2;       // 3200000
    const int Eh = E / 2;                // 1600000 undirected pairs

    float* out_pooled   = (float*)d_out;
    float* out_seg      = out_pooled + (size_t)N * C;
    float* out_scaling  = out_seg + N;
    float* out_cb       = out_scaling + N;
    float* out_ispeak   = out_cb + N;
    float* out_istrough = out_ispeak + N;

    char* p = (char*)d_ws;
    auto alloc = [&](size_t bytes) -> char* {
        char* r = p;
        p += (bytes + 255) & ~(size_t)255;
        return r;
    };
    double* elev64 = (double*)alloc((size_t)N * 8);
    float* elev32  = (float*)alloc((size_t)N * 4);
    int* best      = (int*)alloc((size_t)N * 4);
    int* peakflag  = (int*)alloc((size_t)N * 4);
    int* new_id    = (int*)alloc((size_t)N * 4);
    int* seg       = (int*)alloc((size_t)N * 4);
    float* wbuf    = (float*)alloc((size_t)N * 4);
    const int P = (N + 255) / 256;
    int* part = (int*)alloc((size_t)P * 4);
    int* offs = (int*)alloc((size_t)P * 4);
    unsigned char* code = (unsigned char*)alloc((size_t)Eh);
    char* zbeg = p;  // zero-initialized region starts here
    unsigned char* notpeak   = (unsigned char*)alloc((size_t)N);
    unsigned char* nottrough = (unsigned char*)alloc((size_t)N);
    float* z   = (float*)alloc((size_t)N * 4);
    int* dcnt  = (int*)alloc(2048 * 4);
    size_t zspan = (size_t)(p - zbeg);
    int2* down0 = (int2*)alloc((size_t)E * 8);
    int2* down1 = (int2*)alloc((size_t)E * 8);
    (void)ws_size;

    hipMemsetAsync(zbeg, 0, zspan, stream);
    hipMemsetAsync(out_pooled, 0, (size_t)N * C * sizeof(float), stream);

    const int B4 = (Eh + 1023) / 1024;   // 4 pairs per thread

    k_matvec<<<(N + 3) / 4, 256, 0, stream>>>(x, W, b, elev64, elev32, N, C);
    k_mark<<<B4, 256, 0, stream>>>(ei, elev64, notpeak, nottrough, code, Eh, E);
    k_nodes1<<<P, 256, 0, stream>>>(notpeak, nottrough, peakflag, best,
                                    out_ispeak, out_istrough, out_cb, part, N);
    // new_id = inclusive_scan(peakflag) - 1  (partials already in part)
    k_scan_offs<<<1, 64, 0, stream>>>(part, offs, P);
    k_scan_final<<<P, 256, 0, stream>>>(peakflag, offs, new_id, N);

    // fused build + level 1: kept list lands in down1 with count dcnt[1]
    k_build_l1<<<B4, 256, 0, stream>>>(ei, code, notpeak, best, down1, dcnt, Eh, E);
    // levels 2..NLEVELS over shrinking list, kernel-boundary-synchronized
    for (int L = 2; L <= NLEVELS; ++L)
        k_level_e<<<2048, 256, 0, stream>>>(down0, down1, dcnt, best, L);
    k_tail_e<<<1, 1024, 0, stream>>>(down0, down1, dcnt, best);

    k_segw<<<(N + 255) / 256, 256, 0, stream>>>(best, new_id, elev32, batch, seg,
                                                out_seg, out_cb, wbuf, z, N);
    k_pool<<<(N + 3) / 4, 256, 0, stream>>>(x, seg, wbuf, z, out_scaling,
                                            out_pooled, N, C);
}

// Round 12
// 277.835 us; speedup vs baseline: 3.6501x; 1.0201x over previous
//
#include <hip/hip_runtime.h>

#define SENT32 0x7FFFFFFF
#define IDMASK 0x1FFFF
#define RSHIFT 17
#define NLEVELS 8

// block-wide allocation: per-thread cnt -> contiguous base in *gctr.
// lds must be int[8]. Two __syncthreads inside; caller must barrier before
// reusing lds in a loop.
__device__ __forceinline__ int block_alloc(int cnt, int* gctr, int* lds) {
    int lane = threadIdx.x & 63, wid = threadIdx.x >> 6;
    int pfx = cnt;
#pragma unroll
    for (int off = 1; off < 64; off <<= 1) {
        int t = __shfl_up(pfx, off, 64);
        if (lane >= off) pfx += t;
    }
    if (lane == 63) lds[wid] = pfx;
    __syncthreads();
    if (threadIdx.x == 0) {
        int t = lds[0] + lds[1] + lds[2] + lds[3];
        int bse = t ? atomicAdd(gctr, t) : 0;
        lds[4] = bse;
        lds[5] = bse + lds[0];
        lds[6] = lds[5] + lds[1];
        lds[7] = lds[6] + lds[2];
    }
    __syncthreads();
    return lds[4 + wid] + pfx - cnt;
}

// ---- 1. elevation: elev = x @ W + b, f64 accumulation, wave-per-row ----
__global__ __launch_bounds__(256) void k_matvec(const float* __restrict__ x,
                                                const float* __restrict__ W,
                                                const float* __restrict__ b,
                                                double* __restrict__ elev64,
                                                float* __restrict__ elev32,
                                                int N, int C) {
    int lane = threadIdx.x & 63;
    int wib  = threadIdx.x >> 6;
    int row  = blockIdx.x * (blockDim.x >> 6) + wib;
    if (row >= N) return;
    const float* xr = x + (size_t)row * C;
    double s = 0.0;
    for (int c = lane; c < C; c += 64) s += (double)xr[c] * (double)W[c];
#pragma unroll
    for (int off = 32; off > 0; off >>= 1) s += __shfl_down(s, off, 64);
    if (lane == 0) {
        double v = s + (double)b[0];
        elev64[row] = v;
        elev32[row] = (float)v;
    }
}

// ---- 2. mark pass, 4 undirected pairs per thread (input [src||dst;dst||src]):
// peak/trough violation marks + per-pair 2-bit down-direction code. ----
__global__ __launch_bounds__(256) void k_mark(const int* __restrict__ ei,
                                              const double* __restrict__ elev64,
                                              unsigned char* __restrict__ notpeak,
                                              unsigned char* __restrict__ nottrough,
                                              unsigned char* __restrict__ code,
                                              int Eh, int E) {
    int t0 = (blockIdx.x * 256 + threadIdx.x) * 4;
    if (t0 >= Eh) return;
    bool v0 = true, v1 = (t0 + 1 < Eh), v2 = (t0 + 2 < Eh), v3 = (t0 + 3 < Eh);
    int s0 = 0, s1 = 0, s2 = 0, s3 = 0, d0 = 0, d1 = 0, d2 = 0, d3 = 0;
    if (v3) {
        int4 sv = *(const int4*)&ei[t0];
        int4 dv = *(const int4*)&ei[(size_t)E + t0];
        s0 = sv.x; s1 = sv.y; s2 = sv.z; s3 = sv.w;
        d0 = dv.x; d1 = dv.y; d2 = dv.z; d3 = dv.w;
    } else {
        s0 = ei[t0];            d0 = ei[(size_t)E + t0];
        if (v1) { s1 = ei[t0 + 1]; d1 = ei[(size_t)E + t0 + 1]; }
        if (v2) { s2 = ei[t0 + 2]; d2 = ei[(size_t)E + t0 + 2]; }
    }
    double es0 = elev64[s0], es1 = elev64[s1], es2 = elev64[s2], es3 = elev64[s3];
    double ed0 = elev64[d0], ed1 = elev64[d1], ed2 = elev64[d2], ed3 = elev64[d3];
    unsigned cw = 0;
#define MARK1(J, VV, SS, DD, ES, ED)                                          \
    if (VV) {                                                                 \
        if (ED < ES)      { notpeak[DD] = 1; nottrough[SS] = 1; }             \
        else if (ED > ES) { notpeak[SS] = 1; nottrough[DD] = 1; }             \
        cw |= ((ED <= ES ? 1u : 0u) | (ES <= ED ? 2u : 0u)) << (8 * J);       \
    }
    MARK1(0, v0, s0, d0, es0, ed0)
    MARK1(1, v1, s1, d1, es1, ed1)
    MARK1(2, v2, s2, d2, es2, ed2)
    MARK1(3, v3, s3, d3, es3, ed3)
#undef MARK1
    if (v3) {
        *(unsigned*)&code[t0] = cw;
    } else {
        code[t0] = (unsigned char)(cw & 0xFF);
        if (v1) code[t0 + 1] = (unsigned char)((cw >> 8) & 0xFF);
        if (v2) code[t0 + 2] = (unsigned char)((cw >> 16) & 0xFF);
    }
}

// ---- 3. node pass: flags, best/rnd init, per-block peak partials ----
__global__ __launch_bounds__(256) void k_nodes1(const unsigned char* __restrict__ notpeak,
                                                const unsigned char* __restrict__ nottrough,
                                                int* __restrict__ peakflag,
                                                int* __restrict__ best,
                                                unsigned char* __restrict__ rnd,
                                                float* __restrict__ out_ispeak,
                                                float* __restrict__ out_istrough,
                                                float* __restrict__ out_cb,
                                                int* __restrict__ part, int N) {
    __shared__ int ws[4];
    int n = blockIdx.x * 256 + threadIdx.x;
    int lane = threadIdx.x & 63, wid = threadIdx.x >> 6;
    int pk = 0;
    if (n < N) {
        pk = notpeak[n] ? 0 : 1;
        int tr = nottrough[n] ? 0 : 1;
        peakflag[n] = pk;
        out_ispeak[n] = (float)pk;
        out_istrough[n] = (float)tr;
        best[n] = pk ? n : SENT32;
        rnd[n] = pk ? 0 : 0xFF;          // assignment round, 0xFF = unassigned
        out_cb[n] = -1.0f;
    }
    unsigned long long mk = __ballot(pk);
    if (lane == 0) ws[wid] = __popcll(mk);
    __syncthreads();
    if (threadIdx.x == 0) part[blockIdx.x] = ws[0] + ws[1] + ws[2] + ws[3];
}

// ---- 4. prefix sums (for new_id only) ----
__global__ __launch_bounds__(64) void k_scan_offs(const int* __restrict__ part,
                                                  int* __restrict__ offs, int P) {
    int lane = threadIdx.x;
    int chunk = (P + 63) / 64;
    int s0 = lane * chunk, s1 = min(s0 + chunk, P);
    int s = 0;
    for (int j = s0; j < s1; ++j) s += part[j];
    int incl = s;
#pragma unroll
    for (int off = 1; off < 64; off <<= 1) {
        int t = __shfl_up(incl, off, 64);
        if (lane >= off) incl += t;
    }
    int run = incl - s;
    for (int j = s0; j < s1; ++j) { offs[j] = run; run += part[j]; }
}

__global__ __launch_bounds__(256) void k_scan_final(const int* __restrict__ flag,
                                                    const int* __restrict__ offs,
                                                    int* __restrict__ out0, int N) {
    __shared__ int tmp[256];
    int n = blockIdx.x * 256 + threadIdx.x;
    int f = (n < N) ? flag[n] : 0;
    tmp[threadIdx.x] = f;
    __syncthreads();
    for (int off = 1; off < 256; off <<= 1) {
        int t = (threadIdx.x >= off) ? tmp[threadIdx.x - off] : 0;
        __syncthreads();
        tmp[threadIdx.x] += t;
        __syncthreads();
    }
    if (n < N) out0[n] = offs[blockIdx.x] + tmp[threadIdx.x] - 1;  // new_id
}

// ---- 5a. fused down-list build + BFS level 1, 4 pairs per thread ----
// Level-1 relaxations come only from peak sources: cand = (1<<17)|src, no
// best[] gather (peak flags are stable -> race-free). First-assigner also
// records rnd[d]=1 (unique: old==SENT32 exactly once). Keep an edge for
// levels >= 2 iff BOTH endpoints are non-peak.
__global__ __launch_bounds__(256) void k_build_l1(const int* __restrict__ ei,
                                                  const unsigned char* __restrict__ code,
                                                  const unsigned char* __restrict__ notpeak,
                                                  int* __restrict__ best,
                                                  unsigned char* __restrict__ rnd,
                                                  int2* __restrict__ dst,
                                                  int* __restrict__ dcnt,
                                                  int Eh, int E) {
    __shared__ int lds[8];
    int t0 = (blockIdx.x * 256 + threadIdx.x) * 4;
    bool in = (t0 < Eh);
    bool v0 = in, v1 = (t0 + 1 < Eh), v2 = (t0 + 2 < Eh), v3 = (t0 + 3 < Eh);
    int s0 = 0, s1 = 0, s2 = 0, s3 = 0, d0 = 0, d1 = 0, d2 = 0, d3 = 0;
    unsigned cw = 0;
    if (v3) {
        int4 sv = *(const int4*)&ei[t0];
        int4 dv = *(const int4*)&ei[(size_t)E + t0];
        s0 = sv.x; s1 = sv.y; s2 = sv.z; s3 = sv.w;
        d0 = dv.x; d1 = dv.y; d2 = dv.z; d3 = dv.w;
        cw = *(const unsigned*)&code[t0];
    } else if (in) {
        s0 = ei[t0];            d0 = ei[(size_t)E + t0];
        cw = (unsigned)code[t0];
        if (v1) { s1 = ei[t0 + 1]; d1 = ei[(size_t)E + t0 + 1];
                  cw |= (unsigned)code[t0 + 1] << 8; }
        if (v2) { s2 = ei[t0 + 2]; d2 = ei[(size_t)E + t0 + 2];
                  cw |= (unsigned)code[t0 + 2] << 16; }
    }
    unsigned char np_s0 = notpeak[s0], np_s1 = notpeak[s1],
                  np_s2 = notpeak[s2], np_s3 = notpeak[s3];
    unsigned char np_d0 = notpeak[d0], np_d1 = notpeak[d1],
                  np_d2 = notpeak[d2], np_d3 = notpeak[d3];
    bool ka0 = false, ka1 = false, ka2 = false, ka3 = false;
    bool kb0 = false, kb1 = false, kb2 = false, kb3 = false;
    int cnt = 0;
#define BUILD1(J, VV, SS, DD, NPS, NPD, KA, KB)                               \
    if (VV) {                                                                 \
        unsigned cd = (cw >> (8 * J)) & 0xFFu;                                \
        bool ps = !NPS, pd = !NPD;                                            \
        if (cd & 1u) {                                                        \
            if (ps) {                                                         \
                if (!pd) {                                                    \
                    int old = atomicMin(&best[DD], (1 << RSHIFT) | SS);       \
                    if (old == SENT32) rnd[DD] = 1;                           \
                }                                                             \
            } else if (!pd) { KA = true; ++cnt; }                             \
        }                                                                     \
        if (cd & 2u) {                                                        \
            if (pd) {                                                         \
                if (!ps) {                                                    \
                    int old = atomicMin(&best[SS], (1 << RSHIFT) | DD);       \
                    if (old == SENT32) rnd[SS] = 1;                           \
                }                                                             \
            } else if (!ps) { KB = true; ++cnt; }                             \
        }                                                                     \
    }
    BUILD1(0, v0, s0, d0, np_s0, np_d0, ka0, kb0)
    BUILD1(1, v1, s1, d1, np_s1, np_d1, ka1, kb1)
    BUILD1(2, v2, s2, d2, np_s2, np_d2, ka2, kb2)
    BUILD1(3, v3, s3, d3, np_s3, np_d3, ka3, kb3)
#undef BUILD1
    int base = block_alloc(cnt, &dcnt[1], lds);
    if (ka0) dst[base++] = make_int2(s0, d0);
    if (kb0) dst[base++] = make_int2(d0, s0);
    if (ka1) dst[base++] = make_int2(s1, d1);
    if (kb1) dst[base++] = make_int2(d1, s1);
    if (ka2) dst[base++] = make_int2(s2, d2);
    if (kb2) dst[base++] = make_int2(d2, s2);
    if (ka3) dst[base++] = make_int2(s3, d3);
    if (kb3) dst[base]   = make_int2(d3, s3);
}

// ---- 5b. one BFS level (L>=2): 4 edges/thread, rnd[] byte prefilters ----
// rnd[s]==L-1 (written last sweep, frozen now) -> frontier: gather best[s]
// (final for round L-1: no round-L write can lower it) and atomicMin unless
// rnd[d] < L (assigned earlier => unbeatable). rnd[d]==L or stale 0xFF ->
// atomic arbitrates. Non-frontier src: keep iff rnd[d]==0xFF (a concurrent
// same-sweep assignment of d makes the edge useless: future cand round >=
// L+1 > L). First-assigner (old==SENT32, unique) stores rnd[d]=L.
__global__ __launch_bounds__(256) void k_level_e(int2* __restrict__ d0p,
                                                 int2* __restrict__ d1p,
                                                 int* __restrict__ dcnt,
                                                 int* __restrict__ best,
                                                 unsigned char* __restrict__ rnd,
                                                 int L) {
    int ne = dcnt[L - 1];
    if (ne == 0) return;
    const int2* src = ((L - 1) & 1) ? d1p : d0p;
    int2* dst = (L & 1) ? d1p : d0p;
    __shared__ int lds[8];
    const unsigned char Lf = (unsigned char)(L - 1), Lc = (unsigned char)L;
    int stride = gridDim.x * 1024;
    for (int base = blockIdx.x * 1024; base < ne; base += stride) {
        int i0 = base + threadIdx.x * 4;
        int2 e0 = make_int2(0, 0), e1 = e0, e2 = e0, e3 = e0;
        bool v0 = (i0 < ne), v1 = (i0 + 1 < ne), v2 = (i0 + 2 < ne), v3 = (i0 + 3 < ne);
        if (v3) {
            int4 a = *(const int4*)&src[i0];
            int4 b2 = *(const int4*)&src[i0 + 2];
            e0 = make_int2(a.x, a.y);   e1 = make_int2(a.z, a.w);
            e2 = make_int2(b2.x, b2.y); e3 = make_int2(b2.z, b2.w);
        } else {
            if (v0) e0 = src[i0];
            if (v1) e1 = src[i0 + 1];
            if (v2) e2 = src[i0 + 2];
        }
        unsigned char rs0 = rnd[e0.x], rs1 = rnd[e1.x], rs2 = rnd[e2.x], rs3 = rnd[e3.x];
        unsigned char rd0 = rnd[e0.y], rd1 = rnd[e1.y], rd2 = rnd[e2.y], rd3 = rnd[e3.y];
        bool k0 = false, k1 = false, k2 = false, k3 = false;
        int cnt = 0;
#define LEVEL1(VV, EE, RS, RD, KK)                                            \
    if (VV) {                                                                 \
        if (RS == Lf) {                                                       \
            if (RD >= Lc) {                                                   \
                int old = atomicMin(&best[EE.y], best[EE.x] + (1 << RSHIFT)); \
                if (old == SENT32) rnd[EE.y] = Lc;                            \
            }                                                                 \
        } else if (RD == 0xFF) { KK = true; ++cnt; }                          \
    }
        LEVEL1(v0, e0, rs0, rd0, k0)
        LEVEL1(v1, e1, rs1, rd1, k1)
        LEVEL1(v2, e2, rs2, rd2, k2)
        LEVEL1(v3, e3, rs3, rd3, k3)
#undef LEVEL1
        int wbase = block_alloc(cnt, &dcnt[L], lds);
        if (k0) dst[wbase++] = e0;
        if (k1) dst[wbase++] = e1;
        if (k2) dst[wbase++] = e2;
        if (k3) dst[wbase]   = e3;
        __syncthreads();  // lds reused next iteration
    }
}

// ---- 5c. safety net: levels beyond NLEVELS, single block (best-gather
// logic, independent of rnd[]) ----
__global__ __launch_bounds__(1024) void k_tail_e(int2* __restrict__ d0p,
                                                 int2* __restrict__ d1p,
                                                 int* __restrict__ dcnt,
                                                 int* __restrict__ best) {
    for (int L = NLEVELS + 1; L < 2000; ++L) {
        int ne = dcnt[L - 1];
        if (ne == 0) return;
        const int2* src = ((L - 1) & 1) ? d1p : d0p;
        int2* dst = (L & 1) ? d1p : d0p;
        for (int i = threadIdx.x; i < ne; i += blockDim.x) {
            int2 ed = src[i];
            int bs = best[ed.x];
            if ((bs >> RSHIFT) == L - 1) {
                int cand = bs + (1 << RSHIFT);
                if (best[ed.y] > cand) atomicMin(&best[ed.y], cand);
            } else if (best[ed.y] == SENT32) {
                int pos = atomicAdd(&dcnt[L], 1);
                dst[pos] = ed;
            }
        }
        __threadfence();
        __syncthreads();
    }
}

// ---- 6. fused: seg labels + cluster_batch + softmax weight + z.
// segmax[cluster] == elev32[peak] (watershed paths are non-increasing). ----
__global__ __launch_bounds__(256) void k_segw(const int* __restrict__ best,
                                              const int* __restrict__ new_id,
                                              const float* __restrict__ elev32,
                                              const int* __restrict__ batch,
                                              int* __restrict__ seg,
                                              float* __restrict__ out_seg,
                                              float* __restrict__ out_cb,
                                              float* __restrict__ wbuf,
                                              float* __restrict__ z, int N) {
    int n = blockIdx.x * blockDim.x + threadIdx.x;
    if (n >= N) return;
    int a = best[n];
    int sg = 0;
    float wv = 0.0f;
    if (a != SENT32) {
        int pk = a & IDMASK;              // originating peak node id
        sg = new_id[pk];
        if ((a >> RSHIFT) == 0) out_cb[sg] = (float)batch[n];  // peak node
        wv = expf(elev32[n] - elev32[pk]);
        atomicAdd(&z[sg], wv);
    }
    seg[n] = sg;
    out_seg[n] = (float)sg;
    wbuf[n] = wv;
}

// ---- 7. scaling + weighted pooling (wave-per-node, L2-side atomics) ----
__global__ __launch_bounds__(256) void k_pool(const float* __restrict__ x,
                                              const int* __restrict__ seg,
                                              const float* __restrict__ wbuf,
                                              const float* __restrict__ z,
                                              float* __restrict__ out_scaling,
                                              float* __restrict__ out_pooled,
                                              int N, int C) {
    int lane = threadIdx.x & 63;
    int node = blockIdx.x * (blockDim.x >> 6) + (threadIdx.x >> 6);
    if (node >= N) return;
    int sg = seg[node];
    float sc = wbuf[node] / (z[sg] + 1e-12f);
    if (lane == 0) out_scaling[node] = sc;
    const float* xr = x + (size_t)node * C;
    float* pr = out_pooled + (size_t)sg * C;
    for (int c = lane; c < C; c += 64) atomicAdd(&pr[c], xr[c] * sc);
}

extern "C" void kernel_launch(void* const* d_in, const int* in_sizes, int n_in,
                              void* d_out, int out_size, void* d_ws, size_t ws_size,
                              hipStream_t stream) {
    const float* x = (const float*)d_in[0];
    const float* W = (const float*)d_in[1];
    const float* b = (const float*)d_in[2];
    const int* ei = (const int*)d_in[3];
    const int* batch = (const int*)d_in[4];

    const int C = in_sizes[1];           // 128
    const int N = in_sizes[0] / C;       // 100000
    const int E = in_sizes[3] / 2;       // 3200000
    const int Eh = E / 2;                // 1600000 undirected pairs

    float* out_pooled   = (float*)d_out;
    float* out_seg      = out_pooled + (size_t)N * C;
    float* out_scaling  = out_seg + N;
    float* out_cb       = out_scaling + N;
    float* out_ispeak   = out_cb + N;
    float* out_istrough = out_ispeak + N;

    char* p = (char*)d_ws;
    auto alloc = [&](size_t bytes) -> char* {
        char* r = p;
        p += (bytes + 255) & ~(size_t)255;
        return r;
    };
    double* elev64 = (double*)alloc((size_t)N * 8);
    float* elev32  = (float*)alloc((size_t)N * 4);
    int* best      = (int*)alloc((size_t)N * 4);
    int* peakflag  = (int*)alloc((size_t)N * 4);
    int* new_id    = (int*)alloc((size_t)N * 4);
    int* seg       = (int*)alloc((size_t)N * 4);
    float* wbuf    = (float*)alloc((size_t)N * 4);
    unsigned char* rnd = (unsigned char*)alloc((size_t)N);
    const int P = (N + 255) / 256;
    int* part = (int*)alloc((size_t)P * 4);
    int* offs = (int*)alloc((size_t)P * 4);
    unsigned char* code = (unsigned char*)alloc((size_t)Eh);
    char* zbeg = p;  // zero-initialized region starts here
    unsigned char* notpeak   = (unsigned char*)alloc((size_t)N);
    unsigned char* nottrough = (unsigned char*)alloc((size_t)N);
    float* z   = (float*)alloc((size_t)N * 4);
    int* dcnt  = (int*)alloc(2048 * 4);
    size_t zspan = (size_t)(p - zbeg);
    int2* down0 = (int2*)alloc((size_t)E * 8);
    int2* down1 = (int2*)alloc((size_t)E * 8);
    (void)ws_size;

    hipMemsetAsync(zbeg, 0, zspan, stream);
    hipMemsetAsync(out_pooled, 0, (size_t)N * C * sizeof(float), stream);

    const int B4 = (Eh + 1023) / 1024;   // 4 pairs per thread

    k_matvec<<<(N + 3) / 4, 256, 0, stream>>>(x, W, b, elev64, elev32, N, C);
    k_mark<<<B4, 256, 0, stream>>>(ei, elev64, notpeak, nottrough, code, Eh, E);
    k_nodes1<<<P, 256, 0, stream>>>(notpeak, nottrough, peakflag, best, rnd,
                                    out_ispeak, out_istrough, out_cb, part, N);
    // new_id = inclusive_scan(peakflag) - 1  (partials already in part)
    k_scan_offs<<<1, 64, 0, stream>>>(part, offs, P);
    k_scan_final<<<P, 256, 0, stream>>>(peakflag, offs, new_id, N);

    // fused build + level 1: kept list lands in down1 with count dcnt[1]
    k_build_l1<<<B4, 256, 0, stream>>>(ei, code, notpeak, best, rnd, down1,
                                       dcnt, Eh, E);
    // levels 2..NLEVELS over shrinking list, kernel-boundary-synchronized
    for (int L = 2; L <= NLEVELS; ++L)
        k_level_e<<<2048, 256, 0, stream>>>(down0, down1, dcnt, best, rnd, L);
    k_tail_e<<<1, 1024, 0, stream>>>(down0, down1, dcnt, best);

    k_segw<<<(N + 255) / 256, 256, 0, stream>>>(best, new_id, elev32, batch, seg,
                                                out_seg, out_cb, wbuf, z, N);
    k_pool<<<(N + 3) / 4, 256, 0, stream>>>(x, seg, wbuf, z, out_scaling,
                                            out_pooled, N, C);
}

// Round 13
// 245.675 us; speedup vs baseline: 4.1279x; 1.1309x over previous
//
#include <hip/hip_runtime.h>

#define SENT32 0x7FFFFFFF
#define IDMASK 0x1FFFF
#define RSHIFT 17
#define NLEVELS 8

// block-wide allocation: per-thread cnt -> contiguous base in *gctr.
// lds must be int[8]. Two __syncthreads inside; caller must barrier before
// reusing lds in a loop.
__device__ __forceinline__ int block_alloc(int cnt, int* gctr, int* lds) {
    int lane = threadIdx.x & 63, wid = threadIdx.x >> 6;
    int pfx = cnt;
#pragma unroll
    for (int off = 1; off < 64; off <<= 1) {
        int t = __shfl_up(pfx, off, 64);
        if (lane >= off) pfx += t;
    }
    if (lane == 63) lds[wid] = pfx;
    __syncthreads();
    if (threadIdx.x == 0) {
        int t = lds[0] + lds[1] + lds[2] + lds[3];
        int bse = t ? atomicAdd(gctr, t) : 0;
        lds[4] = bse;
        lds[5] = bse + lds[0];
        lds[6] = lds[5] + lds[1];
        lds[7] = lds[6] + lds[2];
    }
    __syncthreads();
    return lds[4 + wid] + pfx - cnt;
}

// ---- 1. elevation: elev = x @ W + b, f64 accumulation, wave-per-row ----
__global__ __launch_bounds__(256) void k_matvec(const float* __restrict__ x,
                                                const float* __restrict__ W,
                                                const float* __restrict__ b,
                                                double* __restrict__ elev64,
                                                float* __restrict__ elev32,
                                                int N, int C) {
    int lane = threadIdx.x & 63;
    int wib  = threadIdx.x >> 6;
    int row  = blockIdx.x * (blockDim.x >> 6) + wib;
    if (row >= N) return;
    const float* xr = x + (size_t)row * C;
    double s = 0.0;
    for (int c = lane; c < C; c += 64) s += (double)xr[c] * (double)W[c];
#pragma unroll
    for (int off = 32; off > 0; off >>= 1) s += __shfl_down(s, off, 64);
    if (lane == 0) {
        double v = s + (double)b[0];
        elev64[row] = v;
        elev32[row] = (float)v;
    }
}

// ---- 2. mark pass, 4 undirected pairs per thread (input [src||dst;dst||src]):
// peak/trough violation marks + per-pair 2-bit down-direction code. ----
__global__ __launch_bounds__(256) void k_mark(const int* __restrict__ ei,
                                              const double* __restrict__ elev64,
                                              unsigned char* __restrict__ notpeak,
                                              unsigned char* __restrict__ nottrough,
                                              unsigned char* __restrict__ code,
                                              int Eh, int E) {
    int t0 = (blockIdx.x * 256 + threadIdx.x) * 4;
    if (t0 >= Eh) return;
    bool v0 = true, v1 = (t0 + 1 < Eh), v2 = (t0 + 2 < Eh), v3 = (t0 + 3 < Eh);
    int s0 = 0, s1 = 0, s2 = 0, s3 = 0, d0 = 0, d1 = 0, d2 = 0, d3 = 0;
    if (v3) {
        int4 sv = *(const int4*)&ei[t0];
        int4 dv = *(const int4*)&ei[(size_t)E + t0];
        s0 = sv.x; s1 = sv.y; s2 = sv.z; s3 = sv.w;
        d0 = dv.x; d1 = dv.y; d2 = dv.z; d3 = dv.w;
    } else {
        s0 = ei[t0];            d0 = ei[(size_t)E + t0];
        if (v1) { s1 = ei[t0 + 1]; d1 = ei[(size_t)E + t0 + 1]; }
        if (v2) { s2 = ei[t0 + 2]; d2 = ei[(size_t)E + t0 + 2]; }
    }
    double es0 = elev64[s0], es1 = elev64[s1], es2 = elev64[s2], es3 = elev64[s3];
    double ed0 = elev64[d0], ed1 = elev64[d1], ed2 = elev64[d2], ed3 = elev64[d3];
    unsigned cw = 0;
#define MARK1(J, VV, SS, DD, ES, ED)                                          \
    if (VV) {                                                                 \
        if (ED < ES)      { notpeak[DD] = 1; nottrough[SS] = 1; }             \
        else if (ED > ES) { notpeak[SS] = 1; nottrough[DD] = 1; }             \
        cw |= ((ED <= ES ? 1u : 0u) | (ES <= ED ? 2u : 0u)) << (8 * J);       \
    }
    MARK1(0, v0, s0, d0, es0, ed0)
    MARK1(1, v1, s1, d1, es1, ed1)
    MARK1(2, v2, s2, d2, es2, ed2)
    MARK1(3, v3, s3, d3, es3, ed3)
#undef MARK1
    if (v3) {
        *(unsigned*)&code[t0] = cw;
    } else {
        code[t0] = (unsigned char)(cw & 0xFF);
        if (v1) code[t0 + 1] = (unsigned char)((cw >> 8) & 0xFF);
        if (v2) code[t0 + 2] = (unsigned char)((cw >> 16) & 0xFF);
    }
}

// ---- 3. node pass: flags, best/rnd init, per-block peak partials ----
__global__ __launch_bounds__(256) void k_nodes1(const unsigned char* __restrict__ notpeak,
                                                const unsigned char* __restrict__ nottrough,
                                                int* __restrict__ peakflag,
                                                int* __restrict__ best,
                                                unsigned char* __restrict__ rnd,
                                                float* __restrict__ out_ispeak,
                                                float* __restrict__ out_istrough,
                                                float* __restrict__ out_cb,
                                                int* __restrict__ part, int N) {
    __shared__ int ws[4];
    int n = blockIdx.x * 256 + threadIdx.x;
    int lane = threadIdx.x & 63, wid = threadIdx.x >> 6;
    int pk = 0;
    if (n < N) {
        pk = notpeak[n] ? 0 : 1;
        int tr = nottrough[n] ? 0 : 1;
        peakflag[n] = pk;
        out_ispeak[n] = (float)pk;
        out_istrough[n] = (float)tr;
        best[n] = pk ? n : SENT32;
        rnd[n] = pk ? 0 : 0xFF;          // assignment round, 0xFF = unassigned
        out_cb[n] = -1.0f;
    }
    unsigned long long mk = __ballot(pk);
    if (lane == 0) ws[wid] = __popcll(mk);
    __syncthreads();
    if (threadIdx.x == 0) part[blockIdx.x] = ws[0] + ws[1] + ws[2] + ws[3];
}

// ---- 4. prefix sums (for new_id only) ----
__global__ __launch_bounds__(64) void k_scan_offs(const int* __restrict__ part,
                                                  int* __restrict__ offs, int P) {
    int lane = threadIdx.x;
    int chunk = (P + 63) / 64;
    int s0 = lane * chunk, s1 = min(s0 + chunk, P);
    int s = 0;
    for (int j = s0; j < s1; ++j) s += part[j];
    int incl = s;
#pragma unroll
    for (int off = 1; off < 64; off <<= 1) {
        int t = __shfl_up(incl, off, 64);
        if (lane >= off) incl += t;
    }
    int run = incl - s;
    for (int j = s0; j < s1; ++j) { offs[j] = run; run += part[j]; }
}

__global__ __launch_bounds__(256) void k_scan_final(const int* __restrict__ flag,
                                                    const int* __restrict__ offs,
                                                    int* __restrict__ out0, int N) {
    __shared__ int tmp[256];
    int n = blockIdx.x * 256 + threadIdx.x;
    int f = (n < N) ? flag[n] : 0;
    tmp[threadIdx.x] = f;
    __syncthreads();
    for (int off = 1; off < 256; off <<= 1) {
        int t = (threadIdx.x >= off) ? tmp[threadIdx.x - off] : 0;
        __syncthreads();
        tmp[threadIdx.x] += t;
        __syncthreads();
    }
    if (n < N) out0[n] = offs[blockIdx.x] + tmp[threadIdx.x] - 1;  // new_id
}

// ---- 5a. BFS level 1: pure streaming relax of peak-adjacent down edges.
// cand = (1<<17)|src for peak src (stable flags, race-free); first-assigner
// records rnd[d]=1. No list materialization (L2 re-streams ei/code). ----
__global__ __launch_bounds__(256) void k_build_l1(const int* __restrict__ ei,
                                                  const unsigned char* __restrict__ code,
                                                  const unsigned char* __restrict__ notpeak,
                                                  int* __restrict__ best,
                                                  unsigned char* __restrict__ rnd,
                                                  int Eh, int E) {
    int t0 = (blockIdx.x * 256 + threadIdx.x) * 4;
    if (t0 >= Eh) return;
    bool v0 = true, v1 = (t0 + 1 < Eh), v2 = (t0 + 2 < Eh), v3 = (t0 + 3 < Eh);
    int s0 = 0, s1 = 0, s2 = 0, s3 = 0, d0 = 0, d1 = 0, d2 = 0, d3 = 0;
    unsigned cw = 0;
    if (v3) {
        int4 sv = *(const int4*)&ei[t0];
        int4 dv = *(const int4*)&ei[(size_t)E + t0];
        s0 = sv.x; s1 = sv.y; s2 = sv.z; s3 = sv.w;
        d0 = dv.x; d1 = dv.y; d2 = dv.z; d3 = dv.w;
        cw = *(const unsigned*)&code[t0];
    } else {
        s0 = ei[t0];            d0 = ei[(size_t)E + t0];
        cw = (unsigned)code[t0];
        if (v1) { s1 = ei[t0 + 1]; d1 = ei[(size_t)E + t0 + 1];
                  cw |= (unsigned)code[t0 + 1] << 8; }
        if (v2) { s2 = ei[t0 + 2]; d2 = ei[(size_t)E + t0 + 2];
                  cw |= (unsigned)code[t0 + 2] << 16; }
    }
    unsigned char np_s0 = notpeak[s0], np_s1 = notpeak[s1],
                  np_s2 = notpeak[s2], np_s3 = notpeak[s3];
    unsigned char np_d0 = notpeak[d0], np_d1 = notpeak[d1],
                  np_d2 = notpeak[d2], np_d3 = notpeak[d3];
#define BUILD1(J, VV, SS, DD, NPS, NPD)                                       \
    if (VV) {                                                                 \
        unsigned cd = (cw >> (8 * J)) & 0xFFu;                                \
        bool ps = !NPS, pd = !NPD;                                            \
        if ((cd & 1u) && ps && !pd) {                                         \
            int old = atomicMin(&best[DD], (1 << RSHIFT) | SS);               \
            if (old == SENT32) rnd[DD] = 1;                                   \
        }                                                                     \
        if ((cd & 2u) && pd && !ps) {                                         \
            int old = atomicMin(&best[SS], (1 << RSHIFT) | DD);               \
            if (old == SENT32) rnd[SS] = 1;                                   \
        }                                                                     \
    }
    BUILD1(0, v0, s0, d0, np_s0, np_d0)
    BUILD1(1, v1, s1, d1, np_s1, np_d1)
    BUILD1(2, v2, s2, d2, np_s2, np_d2)
    BUILD1(3, v3, s3, d3, np_s3, np_d3)
#undef BUILD1
}

// ---- 5a'. snapshot best -> bsnap (read-only gathers stay cache-clean) ----
__global__ __launch_bounds__(256) void k_snap(const int* __restrict__ best,
                                              int* __restrict__ bsnap, int N) {
    int n = blockIdx.x * 256 + threadIdx.x;
    if (n < N) bsnap[n] = best[n];
}

// ---- 5b. BFS level 2: re-stream ei/code with rnd byte filters.
// rnd[s]==1 -> frontier: cand = bsnap[s]+2^17 (bsnap final for round 1,
// never written -> no line thrash); atomicMin unless rnd[d] < 2 (earlier
// round => unbeatable). rnd[s]==0 (peak) -> edge consumed at L1, dead.
// Else (rnd[s] stale-insensitive {2..0xFF}): keep for L3 iff rnd[d]==0xFF.
// First-assigner (old==SENT32) stores rnd[d]=2. Kept pairs -> down0/dcnt[2].
__global__ __launch_bounds__(256) void k_sweep2(const int* __restrict__ ei,
                                                const unsigned char* __restrict__ code,
                                                const int* __restrict__ bsnap,
                                                int* __restrict__ best,
                                                unsigned char* __restrict__ rnd,
                                                int2* __restrict__ dst,
                                                int* __restrict__ dcnt,
                                                int Eh, int E) {
    __shared__ int lds[8];
    int t0 = (blockIdx.x * 256 + threadIdx.x) * 4;
    bool in = (t0 < Eh);
    bool v0 = in, v1 = (t0 + 1 < Eh), v2 = (t0 + 2 < Eh), v3 = (t0 + 3 < Eh);
    int s0 = 0, s1 = 0, s2 = 0, s3 = 0, d0 = 0, d1 = 0, d2 = 0, d3 = 0;
    unsigned cw = 0;
    if (v3) {
        int4 sv = *(const int4*)&ei[t0];
        int4 dv = *(const int4*)&ei[(size_t)E + t0];
        s0 = sv.x; s1 = sv.y; s2 = sv.z; s3 = sv.w;
        d0 = dv.x; d1 = dv.y; d2 = dv.z; d3 = dv.w;
        cw = *(const unsigned*)&code[t0];
    } else if (in) {
        s0 = ei[t0];            d0 = ei[(size_t)E + t0];
        cw = (unsigned)code[t0];
        if (v1) { s1 = ei[t0 + 1]; d1 = ei[(size_t)E + t0 + 1];
                  cw |= (unsigned)code[t0 + 1] << 8; }
        if (v2) { s2 = ei[t0 + 2]; d2 = ei[(size_t)E + t0 + 2];
                  cw |= (unsigned)code[t0 + 2] << 16; }
    }
    unsigned char rs0 = rnd[s0], rs1 = rnd[s1], rs2 = rnd[s2], rs3 = rnd[s3];
    unsigned char rd0 = rnd[d0], rd1 = rnd[d1], rd2 = rnd[d2], rd3 = rnd[d3];
    bool ka0 = false, ka1 = false, ka2 = false, ka3 = false;
    bool kb0 = false, kb1 = false, kb2 = false, kb3 = false;
    int cnt = 0;
#define SWEEP1(J, VV, SS, DD, RS, RD, KA, KB)                                 \
    if (VV) {                                                                 \
        unsigned cd = (cw >> (8 * J)) & 0xFFu;                                \
        if (cd & 1u) {                                                        \
            if (RS == 1) {                                                    \
                if (RD >= 2) {                                                \
                    int old = atomicMin(&best[DD], bsnap[SS] + (1 << RSHIFT));\
                    if (old == SENT32) rnd[DD] = 2;                           \
                }                                                             \
            } else if (RS != 0 && RD == 0xFF) { KA = true; ++cnt; }           \
        }                                                                     \
        if (cd & 2u) {                                                        \
            if (RD == 1) {                                                    \
                if (RS >= 2) {                                                \
                    int old = atomicMin(&best[SS], bsnap[DD] + (1 << RSHIFT));\
                    if (old == SENT32) rnd[SS] = 2;                           \
                }                                                             \
            } else if (RD != 0 && RS == 0xFF) { KB = true; ++cnt; }           \
        }                                                                     \
    }
    SWEEP1(0, v0, s0, d0, rs0, rd0, ka0, kb0)
    SWEEP1(1, v1, s1, d1, rs1, rd1, ka1, kb1)
    SWEEP1(2, v2, s2, d2, rs2, rd2, ka2, kb2)
    SWEEP1(3, v3, s3, d3, rs3, rd3, ka3, kb3)
#undef SWEEP1
    int base = block_alloc(cnt, &dcnt[2], lds);
    if (ka0) dst[base++] = make_int2(s0, d0);
    if (kb0) dst[base++] = make_int2(d0, s0);
    if (ka1) dst[base++] = make_int2(s1, d1);
    if (kb1) dst[base++] = make_int2(d1, s1);
    if (ka2) dst[base++] = make_int2(s2, d2);
    if (kb2) dst[base++] = make_int2(d2, s2);
    if (ka3) dst[base++] = make_int2(s3, d3);
    if (kb3) dst[base]   = make_int2(d3, s3);
}

// ---- 5c. one BFS level (L>=3): 4 edges/thread over shrinking list ----
__global__ __launch_bounds__(256) void k_level_e(int2* __restrict__ d0p,
                                                 int2* __restrict__ d1p,
                                                 int* __restrict__ dcnt,
                                                 int* __restrict__ best,
                                                 unsigned char* __restrict__ rnd,
                                                 int L) {
    int ne = dcnt[L - 1];
    if (ne == 0) return;
    const int2* src = ((L - 1) & 1) ? d1p : d0p;
    int2* dst = (L & 1) ? d1p : d0p;
    __shared__ int lds[8];
    const unsigned char Lf = (unsigned char)(L - 1), Lc = (unsigned char)L;
    int stride = gridDim.x * 1024;
    for (int base = blockIdx.x * 1024; base < ne; base += stride) {
        int i0 = base + threadIdx.x * 4;
        int2 e0 = make_int2(0, 0), e1 = e0, e2 = e0, e3 = e0;
        bool v0 = (i0 < ne), v1 = (i0 + 1 < ne), v2 = (i0 + 2 < ne), v3 = (i0 + 3 < ne);
        if (v3) {
            int4 a = *(const int4*)&src[i0];
            int4 b2 = *(const int4*)&src[i0 + 2];
            e0 = make_int2(a.x, a.y);   e1 = make_int2(a.z, a.w);
            e2 = make_int2(b2.x, b2.y); e3 = make_int2(b2.z, b2.w);
        } else {
            if (v0) e0 = src[i0];
            if (v1) e1 = src[i0 + 1];
            if (v2) e2 = src[i0 + 2];
        }
        unsigned char rs0 = rnd[e0.x], rs1 = rnd[e1.x], rs2 = rnd[e2.x], rs3 = rnd[e3.x];
        unsigned char rd0 = rnd[e0.y], rd1 = rnd[e1.y], rd2 = rnd[e2.y], rd3 = rnd[e3.y];
        bool k0 = false, k1 = false, k2 = false, k3 = false;
        int cnt = 0;
#define LEVEL1(VV, EE, RS, RD, KK)                                            \
    if (VV) {                                                                 \
        if (RS == Lf) {                                                       \
            if (RD >= Lc) {                                                   \
                int old = atomicMin(&best[EE.y], best[EE.x] + (1 << RSHIFT)); \
                if (old == SENT32) rnd[EE.y] = Lc;                            \
            }                                                                 \
        } else if (RD == 0xFF) { KK = true; ++cnt; }                          \
    }
        LEVEL1(v0, e0, rs0, rd0, k0)
        LEVEL1(v1, e1, rs1, rd1, k1)
        LEVEL1(v2, e2, rs2, rd2, k2)
        LEVEL1(v3, e3, rs3, rd3, k3)
#undef LEVEL1
        int wbase = block_alloc(cnt, &dcnt[L], lds);
        if (k0) dst[wbase++] = e0;
        if (k1) dst[wbase++] = e1;
        if (k2) dst[wbase++] = e2;
        if (k3) dst[wbase]   = e3;
        __syncthreads();  // lds reused next iteration
    }
}

// ---- 5d. safety net: levels beyond NLEVELS, single block ----
__global__ __launch_bounds__(1024) void k_tail_e(int2* __restrict__ d0p,
                                                 int2* __restrict__ d1p,
                                                 int* __restrict__ dcnt,
                                                 int* __restrict__ best) {
    for (int L = NLEVELS + 1; L < 2000; ++L) {
        int ne = dcnt[L - 1];
        if (ne == 0) return;
        const int2* src = ((L - 1) & 1) ? d1p : d0p;
        int2* dst = (L & 1) ? d1p : d0p;
        for (int i = threadIdx.x; i < ne; i += blockDim.x) {
            int2 ed = src[i];
            int bs = best[ed.x];
            if ((bs >> RSHIFT) == L - 1) {
                int cand = bs + (1 << RSHIFT);
                if (best[ed.y] > cand) atomicMin(&best[ed.y], cand);
            } else if (best[ed.y] == SENT32) {
                int pos = atomicAdd(&dcnt[L], 1);
                dst[pos] = ed;
            }
        }
        __threadfence();
        __syncthreads();
    }
}

// ---- 6. fused: seg labels + cluster_batch + softmax weight + z.
// segmax[cluster] == elev32[peak] (watershed paths are non-increasing). ----
__global__ __launch_bounds__(256) void k_segw(const int* __restrict__ best,
                                              const int* __restrict__ new_id,
                                              const float* __restrict__ elev32,
                                              const int* __restrict__ batch,
                                              int* __restrict__ seg,
                                              float* __restrict__ out_seg,
                                              float* __restrict__ out_cb,
                                              float* __restrict__ wbuf,
                                              float* __restrict__ z, int N) {
    int n = blockIdx.x * blockDim.x + threadIdx.x;
    if (n >= N) return;
    int a = best[n];
    int sg = 0;
    float wv = 0.0f;
    if (a != SENT32) {
        int pk = a & IDMASK;              // originating peak node id
        sg = new_id[pk];
        if ((a >> RSHIFT) == 0) out_cb[sg] = (float)batch[n];  // peak node
        wv = expf(elev32[n] - elev32[pk]);
        atomicAdd(&z[sg], wv);
    }
    seg[n] = sg;
    out_seg[n] = (float)sg;
    wbuf[n] = wv;
}

// ---- 7. scaling + weighted pooling (wave-per-node, L2-side atomics) ----
__global__ __launch_bounds__(256) void k_pool(const float* __restrict__ x,
                                              const int* __restrict__ seg,
                                              const float* __restrict__ wbuf,
                                              const float* __restrict__ z,
                                              float* __restrict__ out_scaling,
                                              float* __restrict__ out_pooled,
                                              int N, int C) {
    int lane = threadIdx.x & 63;
    int node = blockIdx.x * (blockDim.x >> 6) + (threadIdx.x >> 6);
    if (node >= N) return;
    int sg = seg[node];
    float sc = wbuf[node] / (z[sg] + 1e-12f);
    if (lane == 0) out_scaling[node] = sc;
    const float* xr = x + (size_t)node * C;
    float* pr = out_pooled + (size_t)sg * C;
    for (int c = lane; c < C; c += 64) atomicAdd(&pr[c], xr[c] * sc);
}

extern "C" void kernel_launch(void* const* d_in, const int* in_sizes, int n_in,
                              void* d_out, int out_size, void* d_ws, size_t ws_size,
                              hipStream_t stream) {
    const float* x = (const float*)d_in[0];
    const float* W = (const float*)d_in[1];
    const float* b = (const float*)d_in[2];
    const int* ei = (const int*)d_in[3];
    const int* batch = (const int*)d_in[4];

    const int C = in_sizes[1];           // 128
    const int N = in_sizes[0] / C;       // 100000
    const int E = in_sizes[3] / 2;       // 3200000
    const int Eh = E / 2;                // 1600000 undirected pairs

    float* out_pooled   = (float*)d_out;
    float* out_seg      = out_pooled + (size_t)N * C;
    float* out_scaling  = out_seg + N;
    float* out_cb       = out_scaling + N;
    float* out_ispeak   = out_cb + N;
    float* out_istrough = out_ispeak + N;

    char* p = (char*)d_ws;
    auto alloc = [&](size_t bytes) -> char* {
        char* r = p;
        p += (bytes + 255) & ~(size_t)255;
        return r;
    };
    double* elev64 = (double*)alloc((size_t)N * 8);
    float* elev32  = (float*)alloc((size_t)N * 4);
    int* best      = (int*)alloc((size_t)N * 4);
    int* bsnap     = (int*)alloc((size_t)N * 4);
    int* peakflag  = (int*)alloc((size_t)N * 4);
    int* new_id    = (int*)alloc((size_t)N * 4);
    int* seg       = (int*)alloc((size_t)N * 4);
    float* wbuf    = (float*)alloc((size_t)N * 4);
    unsigned char* rnd = (unsigned char*)alloc((size_t)N);
    const int P = (N + 255) / 256;
    int* part = (int*)alloc((size_t)P * 4);
    int* offs = (int*)alloc((size_t)P * 4);
    unsigned char* code = (unsigned char*)alloc((size_t)Eh);
    char* zbeg = p;  // zero-initialized region starts here
    unsigned char* notpeak   = (unsigned char*)alloc((size_t)N);
    unsigned char* nottrough = (unsigned char*)alloc((size_t)N);
    float* z   = (float*)alloc((size_t)N * 4);
    int* dcnt  = (int*)alloc(2048 * 4);
    size_t zspan = (size_t)(p - zbeg);
    int2* down0 = (int2*)alloc((size_t)E * 8);
    int2* down1 = (int2*)alloc((size_t)E * 8);
    (void)ws_size;

    hipMemsetAsync(zbeg, 0, zspan, stream);
    hipMemsetAsync(out_pooled, 0, (size_t)N * C * sizeof(float), stream);

    const int B4 = (Eh + 1023) / 1024;   // 4 pairs per thread

    k_matvec<<<(N + 3) / 4, 256, 0, stream>>>(x, W, b, elev64, elev32, N, C);
    k_mark<<<B4, 256, 0, stream>>>(ei, elev64, notpeak, nottrough, code, Eh, E);
    k_nodes1<<<P, 256, 0, stream>>>(notpeak, nottrough, peakflag, best, rnd,
                                    out_ispeak, out_istrough, out_cb, part, N);
    // new_id = inclusive_scan(peakflag) - 1  (partials already in part)
    k_scan_offs<<<1, 64, 0, stream>>>(part, offs, P);
    k_scan_final<<<P, 256, 0, stream>>>(peakflag, offs, new_id, N);

    // level 1: streaming relax (no list); then snapshot; then level 2 sweep
    k_build_l1<<<B4, 256, 0, stream>>>(ei, code, notpeak, best, rnd, Eh, E);
    k_snap<<<P, 256, 0, stream>>>(best, bsnap, N);
    k_sweep2<<<B4, 256, 0, stream>>>(ei, code, bsnap, best, rnd, down0, dcnt, Eh, E);

    // levels 3..NLEVELS over shrinking compacted list
    for (int L = 3; L <= NLEVELS; ++L)
        k_level_e<<<2048, 256, 0, stream>>>(down0, down1, dcnt, best, rnd, L);
    k_tail_e<<<1, 1024, 0, stream>>>(down0, down1, dcnt, best);

    k_segw<<<(N + 255) / 256, 256, 0, stream>>>(best, new_id, elev32, batch, seg,
                                                out_seg, out_cb, wbuf, z, N);
    k_pool<<<(N + 3) / 4, 256, 0, stream>>>(x, seg, wbuf, z, out_scaling,
                                            out_pooled, N, C);
}